// Round 5
// baseline (823.836 us; speedup 1.0000x reference)
//
#include <hip/hip_runtime.h>

// GCN 3-layer: N=50000, E=1.6M, D_IN=256, H=128, D_OUT=64, fp32.
// CSR build: split-atomic degree pass (even/odd -> degA/degB halves contention),
// parallel scan, atomic-free scatter fill, per-row col sort (time-local gather
// window for SpMM L2 locality). Per layer: GEMM then CSR-SpMM.

constexpr int DIN = 256;
constexpr int HID = 128;
constexpr int DOUT = 64;

// ---------- degree + slot (single atomic pass, split counters) ----------

__global__ void init_deg_kernel(int* __restrict__ degA, int* __restrict__ degB, int n) {
  int i = blockIdx.x * blockDim.x + threadIdx.x;
  if (i < n) { degA[i] = 1; degB[i] = 0; }  // self-loop counted in degA
}

__global__ void deg_slot_kernel(const int* __restrict__ dst, int* __restrict__ degA,
                                int* __restrict__ degB, int* __restrict__ slot, int e) {
  int i = blockIdx.x * blockDim.x + threadIdx.x;
  if (i >= e) return;
  int d = dst[i];
  if ((i & 1) == 0) slot[i] = atomicAdd(&degA[d], 1);  // old value >= 1
  else              slot[i] = atomicAdd(&degB[d], 1);  // old value >= 0
}

// ---------- 3-phase exclusive scan of (deg-1), 1024 elems / block ----------

__global__ __launch_bounds__(256) void scanA_kernel(const int* __restrict__ degA,
    const int* __restrict__ degB, int* __restrict__ blocksum, int n) {
  __shared__ int sums[256];
  int t = threadIdx.x;
  int base = blockIdx.x * 1024 + t * 4;
  int local = 0;
#pragma unroll
  for (int k = 0; k < 4; ++k) {
    int i = base + k;
    if (i < n) local += degA[i] + degB[i] - 1;
  }
  sums[t] = local;
  __syncthreads();
  for (int off = 128; off > 0; off >>= 1) {
    if (t < off) sums[t] += sums[t + off];
    __syncthreads();
  }
  if (t == 0) blocksum[blockIdx.x] = sums[0];
}

__global__ __launch_bounds__(64) void scanB_kernel(int* __restrict__ blocksum, int nb) {
  int lane = threadIdx.x;
  int carry = 0;
  for (int base = 0; base < nb; base += 64) {
    int i = base + lane;
    int orig = (i < nb) ? blocksum[i] : 0;
    int v = orig;
#pragma unroll
    for (int off = 1; off < 64; off <<= 1) {
      int u = __shfl_up(v, off, 64);
      if (lane >= off) v += u;
    }
    int total = __shfl(v, 63, 64);
    if (i < nb) blocksum[i] = carry + v - orig;  // exclusive
    carry += total;
  }
}

__global__ __launch_bounds__(256) void scanC_kernel(const int* __restrict__ degA,
    const int* __restrict__ degB, const int* __restrict__ blocksum,
    int* __restrict__ row_start, int* __restrict__ deg, float* __restrict__ dinv, int n) {
  __shared__ int sums[256];
  int t = threadIdx.x;
  int base = blockIdx.x * 1024 + t * 4;
  int d[4];
  int local = 0;
#pragma unroll
  for (int k = 0; k < 4; ++k) {
    int i = base + k;
    d[k] = (i < n) ? (degA[i] + degB[i]) : 1;
    if (i < n) local += d[k] - 1;
  }
  sums[t] = local;
  __syncthreads();
  for (int off = 1; off < 256; off <<= 1) {
    int v = (t >= off) ? sums[t - off] : 0;
    __syncthreads();
    sums[t] += v;
    __syncthreads();
  }
  int run = blocksum[blockIdx.x] + sums[t] - local;  // exclusive offset
#pragma unroll
  for (int k = 0; k < 4; ++k) {
    int i = base + k;
    if (i < n) {
      row_start[i] = run;
      deg[i] = d[k];
      dinv[i] = rsqrtf((float)d[k]);
      run += d[k] - 1;
    }
  }
}

// ---------- CSR fill: atomic-free scatter using precomputed slot ----------

__global__ void fill_kernel(const int* __restrict__ src, const int* __restrict__ dst,
    const int* __restrict__ slot, const int* __restrict__ row_start,
    const int* __restrict__ degA, int* __restrict__ col, int e) {
  int i = blockIdx.x * blockDim.x + threadIdx.x;
  if (i >= e) return;
  int d = dst[i];
  int s = slot[i];
  int base = row_start[d];
  int pos = ((i & 1) == 0) ? (base + s - 1) : (base + (degA[d] - 1) + s);
  col[pos] = src[i];
}

// ---------- per-row ascending sort of col lists (insertion sort, 1 thread/row) ----------

__global__ void sort_kernel(const int* __restrict__ row_start, const int* __restrict__ deg,
                            int* __restrict__ col, int n) {
  int i = blockIdx.x * blockDim.x + threadIdx.x;
  if (i >= n) return;
  int rs = row_start[i];
  int cnt = deg[i] - 1;
  for (int a = 1; a < cnt; ++a) {
    int v = col[rs + a];
    int b = a - 1;
    while (b >= 0 && col[rs + b] > v) { col[rs + b + 1] = col[rs + b]; --b; }
    col[rs + b + 1] = v;
  }
}

// ---------- fp32 GEMM: C[n,F] = X[n,K] @ W[K,F] ----------

template <int K, int F>
__global__ __launch_bounds__(256) void gemm_kernel(const float* __restrict__ X,
    const float* __restrict__ W, float* __restrict__ C, int n) {
  constexpr int KB = 32;
  constexpr int CG = F / 4;
  constexpr int RG = 256 / CG;
  constexpr int RPT = 64 / RG;
  constexpr int XS = KB + 4;
  __shared__ float Xs[64 * XS];
  __shared__ float Ws[KB * F];
  int tid = threadIdx.x;
  int cg = tid % CG;
  int rg = tid / CG;
  int row0 = blockIdx.x * 64;

  float4 acc[RPT];
#pragma unroll
  for (int r = 0; r < RPT; ++r) acc[r] = make_float4(0.f, 0.f, 0.f, 0.f);

  for (int k0 = 0; k0 < K; k0 += KB) {
    __syncthreads();
    constexpr int XF4 = 64 * KB / 4;
    for (int idx = tid; idx < XF4; idx += 256) {
      int row = idx / (KB / 4);
      int k4 = idx % (KB / 4);
      float4 v = make_float4(0.f, 0.f, 0.f, 0.f);
      if (row0 + row < n)
        v = *(const float4*)(X + (size_t)(row0 + row) * K + k0 + k4 * 4);
      *(float4*)(Xs + row * XS + k4 * 4) = v;
    }
    constexpr int WF4 = KB * F / 4;
    for (int idx = tid; idx < WF4; idx += 256) {
      int wr = idx / (F / 4);
      int wc4 = idx % (F / 4);
      *(float4*)(Ws + wr * F + wc4 * 4) =
          *(const float4*)(W + (size_t)(k0 + wr) * F + wc4 * 4);
    }
    __syncthreads();
#pragma unroll
    for (int kk = 0; kk < KB; kk += 4) {
      float4 xv[RPT];
#pragma unroll
      for (int r = 0; r < RPT; ++r)
        xv[r] = *(const float4*)(Xs + (rg * RPT + r) * XS + kk);
#pragma unroll
      for (int j = 0; j < 4; ++j) {
        float4 w = *(const float4*)(Ws + (kk + j) * F + cg * 4);
#pragma unroll
        for (int r = 0; r < RPT; ++r) {
          float xval = (j == 0) ? xv[r].x : (j == 1) ? xv[r].y : (j == 2) ? xv[r].z : xv[r].w;
          acc[r].x = fmaf(xval, w.x, acc[r].x);
          acc[r].y = fmaf(xval, w.y, acc[r].y);
          acc[r].z = fmaf(xval, w.z, acc[r].z);
          acc[r].w = fmaf(xval, w.w, acc[r].w);
        }
      }
    }
  }
#pragma unroll
  for (int r = 0; r < RPT; ++r) {
    int row = row0 + rg * RPT + r;
    if (row < n) *(float4*)(C + (size_t)row * F + cg * 4) = acc[r];
  }
}

// ---------- CSR SpMM: out[i] = dinv[i]^2*t[i] + sum_p dinv[col]*dinv[i]*t[col] + b ----------
// One wave per destination node; unroll 8 for memory-level parallelism.

template <int F, bool RELU>
__global__ __launch_bounds__(256) void spmm_kernel(const float* __restrict__ t,
    const int* __restrict__ row_start, const int* __restrict__ deg,
    const int* __restrict__ col, const float* __restrict__ dinv,
    const float* __restrict__ bias, float* __restrict__ out, int n) {
  int wid = (int)((blockIdx.x * 256u + threadIdx.x) >> 6);
  int lane = threadIdx.x & 63;
  if (wid >= n) return;
  int rs = row_start[wid];
  int cnt = deg[wid] - 1;
  float di = dinv[wid];
  float wself = di * di;

  if constexpr (F == 128) {
    float2 v = ((const float2*)(t + (size_t)wid * F))[lane];
    float ax = wself * v.x;
    float ay = wself * v.y;
    int p = rs, pe = rs + cnt;
    for (; p + 8 <= pe; p += 8) {
      int c[8];
      float w[8];
      float2 vv[8];
#pragma unroll
      for (int j = 0; j < 8; ++j) c[j] = col[p + j];
#pragma unroll
      for (int j = 0; j < 8; ++j) vv[j] = ((const float2*)(t + (size_t)c[j] * F))[lane];
#pragma unroll
      for (int j = 0; j < 8; ++j) w[j] = di * dinv[c[j]];
#pragma unroll
      for (int j = 0; j < 8; ++j) {
        ax = fmaf(w[j], vv[j].x, ax);
        ay = fmaf(w[j], vv[j].y, ay);
      }
    }
    for (; p < pe; ++p) {
      int c = col[p];
      float w = di * dinv[c];
      float2 vv = ((const float2*)(t + (size_t)c * F))[lane];
      ax = fmaf(w, vv.x, ax); ay = fmaf(w, vv.y, ay);
    }
    ax += bias[2 * lane];
    ay += bias[2 * lane + 1];
    if constexpr (RELU) { ax = fmaxf(ax, 0.f); ay = fmaxf(ay, 0.f); }
    float2 o; o.x = ax; o.y = ay;
    ((float2*)(out + (size_t)wid * F))[lane] = o;
  } else {  // F == 64
    float a = wself * t[(size_t)wid * F + lane];
    int p = rs, pe = rs + cnt;
    for (; p + 8 <= pe; p += 8) {
      int c[8];
      float w[8];
      float vv[8];
#pragma unroll
      for (int j = 0; j < 8; ++j) c[j] = col[p + j];
#pragma unroll
      for (int j = 0; j < 8; ++j) vv[j] = t[(size_t)c[j] * F + lane];
#pragma unroll
      for (int j = 0; j < 8; ++j) w[j] = di * dinv[c[j]];
#pragma unroll
      for (int j = 0; j < 8; ++j) a = fmaf(w[j], vv[j], a);
    }
    for (; p < pe; ++p) a = fmaf(di * dinv[col[p]], t[(size_t)col[p] * F + lane], a);
    a += bias[lane];
    if constexpr (RELU) a = fmaxf(a, 0.f);
    out[(size_t)wid * F + lane] = a;
  }
}

// ---------- launch ----------

extern "C" void kernel_launch(void* const* d_in, const int* in_sizes, int n_in,
                              void* d_out, int out_size, void* d_ws, size_t ws_size,
                              hipStream_t stream) {
  const float* x  = (const float*)d_in[0];
  const float* W1 = (const float*)d_in[1];
  const float* b1 = (const float*)d_in[2];
  const float* W2 = (const float*)d_in[3];
  const float* b2 = (const float*)d_in[4];
  const float* W3 = (const float*)d_in[5];
  const float* b3 = (const float*)d_in[6];
  const int* ei   = (const int*)d_in[7];  // harness delivers integers as int32

  int n = in_sizes[0] / DIN;
  int e = in_sizes[7] / 2;
  const int* src = ei;
  const int* dst = ei + e;

  char* ws = (char*)d_ws;
  size_t off = 0;
  auto alloc = [&](size_t bytes) -> void* {
    off = (off + 255) & ~(size_t)255;
    void* p = ws + off;
    off += bytes;
    return p;
  };
  int nscan = (n + 1023) / 1024;
  int*   degA      = (int*)alloc((size_t)n * 4);
  int*   degB      = (int*)alloc((size_t)n * 4);
  int*   deg       = (int*)alloc((size_t)n * 4);
  float* dinv      = (float*)alloc((size_t)n * 4);
  int*   row_start = (int*)alloc((size_t)n * 4);
  int*   blocksum  = (int*)alloc((size_t)nscan * 4);
  int*   slot      = (int*)alloc((size_t)e * 4);
  int*   col       = (int*)alloc((size_t)e * 4);
  float* A         = (float*)alloc((size_t)n * HID * 4);
  float* B         = (float*)alloc((size_t)n * HID * 4);
  (void)ws_size;

  int nb256 = (n + 255) / 256;
  int eb256 = (e + 255) / 256;
  int gemm_blocks = (n + 63) / 64;
  int spmm_blocks = (n + 3) / 4;  // 4 waves / block, 1 wave / node

  init_deg_kernel<<<nb256, 256, 0, stream>>>(degA, degB, n);
  deg_slot_kernel<<<eb256, 256, 0, stream>>>(dst, degA, degB, slot, e);
  scanA_kernel<<<nscan, 256, 0, stream>>>(degA, degB, blocksum, n);
  scanB_kernel<<<1, 64, 0, stream>>>(blocksum, nscan);
  scanC_kernel<<<nscan, 256, 0, stream>>>(degA, degB, blocksum, row_start, deg, dinv, n);
  fill_kernel<<<eb256, 256, 0, stream>>>(src, dst, slot, row_start, degA, col, e);
  sort_kernel<<<nb256, 256, 0, stream>>>(row_start, deg, col, n);

  gemm_kernel<DIN, HID><<<gemm_blocks, 256, 0, stream>>>(x, W1, A, n);
  spmm_kernel<HID, true><<<spmm_blocks, 256, 0, stream>>>(A, row_start, deg, col, dinv, b1, B, n);
  gemm_kernel<HID, HID><<<gemm_blocks, 256, 0, stream>>>(B, W2, A, n);
  spmm_kernel<HID, true><<<spmm_blocks, 256, 0, stream>>>(A, row_start, deg, col, dinv, b2, B, n);
  gemm_kernel<HID, DOUT><<<gemm_blocks, 256, 0, stream>>>(B, W3, A, n);
  spmm_kernel<DOUT, false><<<spmm_blocks, 256, 0, stream>>>(A, row_start, deg, col, dinv, b3, (float*)d_out, n);
}

// Round 6
// 455.413 us; speedup vs baseline: 1.8090x; 1.8090x over previous
//
#include <hip/hip_runtime.h>

// GCN 3-layer: N=50000, E=1.6M, D_IN=256, H=128, D_OUT=64, fp32 in/out.
// CSR build: split-atomic degree pass, parallel scan, atomic-free scatter fill.
// Per layer: fp32 GEMM writing bf16 rows pre-scaled by dinv[row]  ->  CSR-SpMM
// that just SUMS gathered bf16 rows (dinv folded out), final scale+bias+relu.

constexpr int DIN = 256;
constexpr int HID = 128;
constexpr int DOUT = 64;

typedef unsigned short ushort_t;
typedef unsigned int uint_t;

__device__ inline ushort_t f2bf(float f) {
  uint_t u = __float_as_uint(f);
  u += 0x7FFF + ((u >> 16) & 1);  // RNE
  return (ushort_t)(u >> 16);
}
__device__ inline float bf2f(ushort_t b) {
  return __uint_as_float(((uint_t)b) << 16);
}

// ---------- degree + slot (single atomic pass, split counters) ----------

__global__ void init_deg_kernel(int* __restrict__ degA, int* __restrict__ degB, int n) {
  int i = blockIdx.x * blockDim.x + threadIdx.x;
  if (i < n) { degA[i] = 1; degB[i] = 0; }  // self-loop counted in degA
}

__global__ void deg_slot_kernel(const int* __restrict__ dst, int* __restrict__ degA,
                                int* __restrict__ degB, int* __restrict__ slot, int e) {
  int i = blockIdx.x * blockDim.x + threadIdx.x;
  if (i >= e) return;
  int d = dst[i];
  if ((i & 1) == 0) slot[i] = atomicAdd(&degA[d], 1);  // old value >= 1
  else              slot[i] = atomicAdd(&degB[d], 1);  // old value >= 0
}

// ---------- 3-phase exclusive scan of (deg-1), 1024 elems / block ----------

__global__ __launch_bounds__(256) void scanA_kernel(const int* __restrict__ degA,
    const int* __restrict__ degB, int* __restrict__ blocksum, int n) {
  __shared__ int sums[256];
  int t = threadIdx.x;
  int base = blockIdx.x * 1024 + t * 4;
  int local = 0;
#pragma unroll
  for (int k = 0; k < 4; ++k) {
    int i = base + k;
    if (i < n) local += degA[i] + degB[i] - 1;
  }
  sums[t] = local;
  __syncthreads();
  for (int off = 128; off > 0; off >>= 1) {
    if (t < off) sums[t] += sums[t + off];
    __syncthreads();
  }
  if (t == 0) blocksum[blockIdx.x] = sums[0];
}

__global__ __launch_bounds__(64) void scanB_kernel(int* __restrict__ blocksum, int nb) {
  int lane = threadIdx.x;
  int carry = 0;
  for (int base = 0; base < nb; base += 64) {
    int i = base + lane;
    int orig = (i < nb) ? blocksum[i] : 0;
    int v = orig;
#pragma unroll
    for (int off = 1; off < 64; off <<= 1) {
      int u = __shfl_up(v, off, 64);
      if (lane >= off) v += u;
    }
    int total = __shfl(v, 63, 64);
    if (i < nb) blocksum[i] = carry + v - orig;  // exclusive
    carry += total;
  }
}

__global__ __launch_bounds__(256) void scanC_kernel(const int* __restrict__ degA,
    const int* __restrict__ degB, const int* __restrict__ blocksum,
    int* __restrict__ row_start, int* __restrict__ deg, float* __restrict__ dinv, int n) {
  __shared__ int sums[256];
  int t = threadIdx.x;
  int base = blockIdx.x * 1024 + t * 4;
  int d[4];
  int local = 0;
#pragma unroll
  for (int k = 0; k < 4; ++k) {
    int i = base + k;
    d[k] = (i < n) ? (degA[i] + degB[i]) : 1;
    if (i < n) local += d[k] - 1;
  }
  sums[t] = local;
  __syncthreads();
  for (int off = 1; off < 256; off <<= 1) {
    int v = (t >= off) ? sums[t - off] : 0;
    __syncthreads();
    sums[t] += v;
    __syncthreads();
  }
  int run = blocksum[blockIdx.x] + sums[t] - local;  // exclusive offset
#pragma unroll
  for (int k = 0; k < 4; ++k) {
    int i = base + k;
    if (i < n) {
      row_start[i] = run;
      deg[i] = d[k];
      dinv[i] = rsqrtf((float)d[k]);
      run += d[k] - 1;
    }
  }
}

// ---------- CSR fill: atomic-free scatter using precomputed slot ----------

__global__ void fill_kernel(const int* __restrict__ src, const int* __restrict__ dst,
    const int* __restrict__ slot, const int* __restrict__ row_start,
    const int* __restrict__ degA, int* __restrict__ col, int e) {
  int i = blockIdx.x * blockDim.x + threadIdx.x;
  if (i >= e) return;
  int d = dst[i];
  int s = slot[i];
  int base = row_start[d];
  int pos = ((i & 1) == 0) ? (base + s - 1) : (base + (degA[d] - 1) + s);
  col[pos] = src[i];
}

// ---------- fp32 GEMM: C[n,F] = dinv[row] * (X[n,K] @ W[K,F]), bf16 output ----------

template <int K, int F>
__global__ __launch_bounds__(256) void gemm_kernel(const float* __restrict__ X,
    const float* __restrict__ W, const float* __restrict__ dinv,
    ushort_t* __restrict__ C, int n) {
  constexpr int KB = 32;
  constexpr int CG = F / 4;
  constexpr int RG = 256 / CG;
  constexpr int RPT = 64 / RG;
  constexpr int XS = KB + 4;
  __shared__ float Xs[64 * XS];
  __shared__ float Ws[KB * F];
  int tid = threadIdx.x;
  int cg = tid % CG;
  int rg = tid / CG;
  int row0 = blockIdx.x * 64;

  float4 acc[RPT];
#pragma unroll
  for (int r = 0; r < RPT; ++r) acc[r] = make_float4(0.f, 0.f, 0.f, 0.f);

  for (int k0 = 0; k0 < K; k0 += KB) {
    __syncthreads();
    constexpr int XF4 = 64 * KB / 4;
    for (int idx = tid; idx < XF4; idx += 256) {
      int row = idx / (KB / 4);
      int k4 = idx % (KB / 4);
      float4 v = make_float4(0.f, 0.f, 0.f, 0.f);
      if (row0 + row < n)
        v = *(const float4*)(X + (size_t)(row0 + row) * K + k0 + k4 * 4);
      *(float4*)(Xs + row * XS + k4 * 4) = v;
    }
    constexpr int WF4 = KB * F / 4;
    for (int idx = tid; idx < WF4; idx += 256) {
      int wr = idx / (F / 4);
      int wc4 = idx % (F / 4);
      *(float4*)(Ws + wr * F + wc4 * 4) =
          *(const float4*)(W + (size_t)(k0 + wr) * F + wc4 * 4);
    }
    __syncthreads();
#pragma unroll
    for (int kk = 0; kk < KB; kk += 4) {
      float4 xv[RPT];
#pragma unroll
      for (int r = 0; r < RPT; ++r)
        xv[r] = *(const float4*)(Xs + (rg * RPT + r) * XS + kk);
#pragma unroll
      for (int j = 0; j < 4; ++j) {
        float4 w = *(const float4*)(Ws + (kk + j) * F + cg * 4);
#pragma unroll
        for (int r = 0; r < RPT; ++r) {
          float xval = (j == 0) ? xv[r].x : (j == 1) ? xv[r].y : (j == 2) ? xv[r].z : xv[r].w;
          acc[r].x = fmaf(xval, w.x, acc[r].x);
          acc[r].y = fmaf(xval, w.y, acc[r].y);
          acc[r].z = fmaf(xval, w.z, acc[r].z);
          acc[r].w = fmaf(xval, w.w, acc[r].w);
        }
      }
    }
  }
#pragma unroll
  for (int r = 0; r < RPT; ++r) {
    int row = row0 + rg * RPT + r;
    if (row < n) {
      float s = dinv[row];
      ushort4 o;
      o.x = f2bf(s * acc[r].x);
      o.y = f2bf(s * acc[r].y);
      o.z = f2bf(s * acc[r].z);
      o.w = f2bf(s * acc[r].w);
      *(ushort4*)(C + (size_t)row * F + cg * 4) = o;
    }
  }
}

// ---------- CSR SpMM: out[d] = dinv[d]*(t'[d] + sum_c t'[c]) + b, opt ReLU ----------
// t' rows are bf16, pre-scaled by dinv[row]. One wave per destination node.

template <int F, bool RELU>
__global__ __launch_bounds__(256) void spmm_kernel(const ushort_t* __restrict__ t,
    const int* __restrict__ row_start, const int* __restrict__ deg,
    const int* __restrict__ col, const float* __restrict__ dinv,
    const float* __restrict__ bias, float* __restrict__ out, int n) {
  int wid = (int)((blockIdx.x * 256u + threadIdx.x) >> 6);
  int lane = threadIdx.x & 63;
  if (wid >= n) return;
  int rs = row_start[wid];
  int cnt = deg[wid] - 1;
  float di = dinv[wid];

  if constexpr (F == 128) {
    // lane covers cols 2*lane, 2*lane+1 (one uint = 2 bf16)
    uint_t self = ((const uint_t*)(t + (size_t)wid * F))[lane];
    float ax = bf2f((ushort_t)(self & 0xFFFF));
    float ay = bf2f((ushort_t)(self >> 16));
    int p = rs, pe = rs + cnt;
    for (; p + 8 <= pe; p += 8) {
      int c[8];
      uint_t v[8];
#pragma unroll
      for (int j = 0; j < 8; ++j) c[j] = col[p + j];
#pragma unroll
      for (int j = 0; j < 8; ++j) v[j] = ((const uint_t*)(t + (size_t)c[j] * F))[lane];
#pragma unroll
      for (int j = 0; j < 8; ++j) {
        ax += bf2f((ushort_t)(v[j] & 0xFFFF));
        ay += bf2f((ushort_t)(v[j] >> 16));
      }
    }
    for (; p < pe; ++p) {
      uint_t v = ((const uint_t*)(t + (size_t)col[p] * F))[lane];
      ax += bf2f((ushort_t)(v & 0xFFFF));
      ay += bf2f((ushort_t)(v >> 16));
    }
    ax = fmaf(di, ax, bias[2 * lane]);
    ay = fmaf(di, ay, bias[2 * lane + 1]);
    if constexpr (RELU) { ax = fmaxf(ax, 0.f); ay = fmaxf(ay, 0.f); }
    float2 o; o.x = ax; o.y = ay;
    ((float2*)(out + (size_t)wid * F))[lane] = o;
  } else {  // F == 64: one bf16 per lane
    float a = bf2f(t[(size_t)wid * F + lane]);
    int p = rs, pe = rs + cnt;
    for (; p + 8 <= pe; p += 8) {
      int c[8];
      ushort_t v[8];
#pragma unroll
      for (int j = 0; j < 8; ++j) c[j] = col[p + j];
#pragma unroll
      for (int j = 0; j < 8; ++j) v[j] = t[(size_t)c[j] * F + lane];
#pragma unroll
      for (int j = 0; j < 8; ++j) a += bf2f(v[j]);
    }
    for (; p < pe; ++p) a += bf2f(t[(size_t)col[p] * F + lane]);
    a = fmaf(di, a, bias[lane]);
    if constexpr (RELU) a = fmaxf(a, 0.f);
    out[(size_t)wid * F + lane] = a;
  }
}

// ---------- launch ----------

extern "C" void kernel_launch(void* const* d_in, const int* in_sizes, int n_in,
                              void* d_out, int out_size, void* d_ws, size_t ws_size,
                              hipStream_t stream) {
  const float* x  = (const float*)d_in[0];
  const float* W1 = (const float*)d_in[1];
  const float* b1 = (const float*)d_in[2];
  const float* W2 = (const float*)d_in[3];
  const float* b2 = (const float*)d_in[4];
  const float* W3 = (const float*)d_in[5];
  const float* b3 = (const float*)d_in[6];
  const int* ei   = (const int*)d_in[7];  // harness delivers integers as int32

  int n = in_sizes[0] / DIN;
  int e = in_sizes[7] / 2;
  const int* src = ei;
  const int* dst = ei + e;

  char* ws = (char*)d_ws;
  size_t off = 0;
  auto alloc = [&](size_t bytes) -> void* {
    off = (off + 255) & ~(size_t)255;
    void* p = ws + off;
    off += bytes;
    return p;
  };
  int nscan = (n + 1023) / 1024;
  int*      degA      = (int*)alloc((size_t)n * 4);
  int*      degB      = (int*)alloc((size_t)n * 4);
  int*      deg       = (int*)alloc((size_t)n * 4);
  float*    dinv      = (float*)alloc((size_t)n * 4);
  int*      row_start = (int*)alloc((size_t)n * 4);
  int*      blocksum  = (int*)alloc((size_t)nscan * 4);
  int*      slot      = (int*)alloc((size_t)e * 4);
  int*      col       = (int*)alloc((size_t)e * 4);
  ushort_t* T         = (ushort_t*)alloc((size_t)n * HID * 2);  // bf16 GEMM out
  float*    Hf        = (float*)alloc((size_t)n * HID * 4);     // fp32 SpMM out
  (void)ws_size;

  int nb256 = (n + 255) / 256;
  int eb256 = (e + 255) / 256;
  int gemm_blocks = (n + 63) / 64;
  int spmm_blocks = (n + 3) / 4;  // 4 waves / block, 1 wave / node

  init_deg_kernel<<<nb256, 256, 0, stream>>>(degA, degB, n);
  deg_slot_kernel<<<eb256, 256, 0, stream>>>(dst, degA, degB, slot, e);
  scanA_kernel<<<nscan, 256, 0, stream>>>(degA, degB, blocksum, n);
  scanB_kernel<<<1, 64, 0, stream>>>(blocksum, nscan);
  scanC_kernel<<<nscan, 256, 0, stream>>>(degA, degB, blocksum, row_start, deg, dinv, n);
  fill_kernel<<<eb256, 256, 0, stream>>>(src, dst, slot, row_start, degA, col, e);

  gemm_kernel<DIN, HID><<<gemm_blocks, 256, 0, stream>>>(x, W1, dinv, T, n);
  spmm_kernel<HID, true><<<spmm_blocks, 256, 0, stream>>>(T, row_start, deg, col, dinv, b1, Hf, n);
  gemm_kernel<HID, HID><<<gemm_blocks, 256, 0, stream>>>(Hf, W2, dinv, T, n);
  spmm_kernel<HID, true><<<spmm_blocks, 256, 0, stream>>>(T, row_start, deg, col, dinv, b2, Hf, n);
  gemm_kernel<HID, DOUT><<<gemm_blocks, 256, 0, stream>>>(Hf, W3, dinv, T, n);
  spmm_kernel<DOUT, false><<<spmm_blocks, 256, 0, stream>>>(T, row_start, deg, col, dinv, b3, (float*)d_out, n);
}

// Round 7
// 453.419 us; speedup vs baseline: 1.8169x; 1.0044x over previous
//
#include <hip/hip_runtime.h>

// GCN 3-layer: N=50000, E=1.6M, D_IN=256, H=128, D_OUT=64, fp32 in/out.
// CSR build: 4-way split-atomic degree pass (atomic return = slot), parallel
// scan with per-node int4 sub-base table, atomic-free scatter fill.
// Per layer: fp32 GEMM writing bf16 rows pre-scaled by dinv[row] -> CSR-SpMM
// that sums gathered bf16 rows (2 dst nodes per wave for MLP), scale+bias+relu.

constexpr int DIN = 256;
constexpr int HID = 128;
constexpr int DOUT = 64;

typedef unsigned short ushort_t;
typedef unsigned int uint_t;

__device__ inline ushort_t f2bf(float f) {
  uint_t u = __float_as_uint(f);
  u += 0x7FFF + ((u >> 16) & 1);  // RNE
  return (ushort_t)(u >> 16);
}
__device__ inline float bf2f(ushort_t b) {
  return __uint_as_float(((uint_t)b) << 16);
}

// ---------- degree + slot (single atomic pass, 4-way split counters) ----------

__global__ void init_deg_kernel(int* __restrict__ c0, int* __restrict__ c1,
                                int* __restrict__ c2, int* __restrict__ c3, int n) {
  int i = blockIdx.x * blockDim.x + threadIdx.x;
  if (i < n) { c0[i] = 1; c1[i] = 0; c2[i] = 0; c3[i] = 0; }  // self-loop in c0
}

__global__ void deg_slot_kernel(const int* __restrict__ dst, int* __restrict__ c0,
                                int* __restrict__ c1, int* __restrict__ c2,
                                int* __restrict__ c3, int* __restrict__ slot, int e) {
  int i = blockIdx.x * blockDim.x + threadIdx.x;
  if (i >= e) return;
  int d = dst[i];
  int k = i & 3;
  int s;
  if      (k == 0) s = atomicAdd(&c0[d], 1);  // >= 1
  else if (k == 1) s = atomicAdd(&c1[d], 1);  // >= 0
  else if (k == 2) s = atomicAdd(&c2[d], 1);
  else             s = atomicAdd(&c3[d], 1);
  slot[i] = s;
}

// ---------- 3-phase exclusive scan of (deg-1), 1024 elems / block ----------

__global__ __launch_bounds__(256) void scanA_kernel(const int* __restrict__ c0,
    const int* __restrict__ c1, const int* __restrict__ c2, const int* __restrict__ c3,
    int* __restrict__ blocksum, int n) {
  __shared__ int sums[256];
  int t = threadIdx.x;
  int base = blockIdx.x * 1024 + t * 4;
  int local = 0;
#pragma unroll
  for (int k = 0; k < 4; ++k) {
    int i = base + k;
    if (i < n) local += c0[i] + c1[i] + c2[i] + c3[i] - 1;
  }
  sums[t] = local;
  __syncthreads();
  for (int off = 128; off > 0; off >>= 1) {
    if (t < off) sums[t] += sums[t + off];
    __syncthreads();
  }
  if (t == 0) blocksum[blockIdx.x] = sums[0];
}

__global__ __launch_bounds__(64) void scanB_kernel(int* __restrict__ blocksum, int nb) {
  int lane = threadIdx.x;
  int carry = 0;
  for (int base = 0; base < nb; base += 64) {
    int i = base + lane;
    int orig = (i < nb) ? blocksum[i] : 0;
    int v = orig;
#pragma unroll
    for (int off = 1; off < 64; off <<= 1) {
      int u = __shfl_up(v, off, 64);
      if (lane >= off) v += u;
    }
    int total = __shfl(v, 63, 64);
    if (i < nb) blocksum[i] = carry + v - orig;  // exclusive
    carry += total;
  }
}

// Phase C: row_start/deg/dinv + int4 sub-base table for the 4 slot classes.
__global__ __launch_bounds__(256) void scanC_kernel(const int* __restrict__ c0,
    const int* __restrict__ c1, const int* __restrict__ c2, const int* __restrict__ c3,
    const int* __restrict__ blocksum, int* __restrict__ row_start, int* __restrict__ deg,
    float* __restrict__ dinv, int4* __restrict__ sub, int n) {
  __shared__ int sums[256];
  int t = threadIdx.x;
  int base = blockIdx.x * 1024 + t * 4;
  int d[4], k0[4], k1[4], k2[4];
  int local = 0;
#pragma unroll
  for (int k = 0; k < 4; ++k) {
    int i = base + k;
    if (i < n) {
      k0[k] = c0[i]; k1[k] = c1[i]; k2[k] = c2[i];
      d[k] = k0[k] + k1[k] + k2[k] + c3[i];
      local += d[k] - 1;
    } else { d[k] = 1; k0[k] = 1; k1[k] = 0; k2[k] = 0; }
  }
  sums[t] = local;
  __syncthreads();
  for (int off = 1; off < 256; off <<= 1) {
    int v = (t >= off) ? sums[t - off] : 0;
    __syncthreads();
    sums[t] += v;
    __syncthreads();
  }
  int run = blocksum[blockIdx.x] + sums[t] - local;  // exclusive offset
#pragma unroll
  for (int k = 0; k < 4; ++k) {
    int i = base + k;
    if (i < n) {
      row_start[i] = run;
      deg[i] = d[k];
      dinv[i] = rsqrtf((float)d[k]);
      int4 sb;
      sb.x = run - 1;                  // class 0: slot >= 1 -> pos = run-1+slot
      sb.y = run + (k0[k] - 1);        // class 1: slot >= 0
      sb.z = sb.y + k1[k];             // class 2
      sb.w = sb.z + k2[k];             // class 3
      sub[i] = sb;
      run += d[k] - 1;
    }
  }
}

// ---------- CSR fill: atomic-free scatter, one int4 gather per edge ----------

__global__ void fill_kernel(const int* __restrict__ src, const int* __restrict__ dst,
    const int* __restrict__ slot, const int4* __restrict__ sub,
    int* __restrict__ col, int e) {
  int i = blockIdx.x * blockDim.x + threadIdx.x;
  if (i >= e) return;
  int d = dst[i];
  int k = i & 3;
  int4 sb = sub[d];
  int base = (k == 0) ? sb.x : (k == 1) ? sb.y : (k == 2) ? sb.z : sb.w;
  col[base + slot[i]] = src[i];
}

// ---------- fp32 GEMM: C[n,F] = dinv[row] * (X[n,K] @ W[K,F]), bf16 output ----------

template <int K, int F>
__global__ __launch_bounds__(256) void gemm_kernel(const float* __restrict__ X,
    const float* __restrict__ W, const float* __restrict__ dinv,
    ushort_t* __restrict__ C, int n) {
  constexpr int KB = 32;
  constexpr int CG = F / 4;
  constexpr int RG = 256 / CG;
  constexpr int RPT = 64 / RG;
  constexpr int XS = KB + 4;
  __shared__ float Xs[64 * XS];
  __shared__ float Ws[KB * F];
  int tid = threadIdx.x;
  int cg = tid % CG;
  int rg = tid / CG;
  int row0 = blockIdx.x * 64;

  float4 acc[RPT];
#pragma unroll
  for (int r = 0; r < RPT; ++r) acc[r] = make_float4(0.f, 0.f, 0.f, 0.f);

  for (int k0 = 0; k0 < K; k0 += KB) {
    __syncthreads();
    constexpr int XF4 = 64 * KB / 4;
    for (int idx = tid; idx < XF4; idx += 256) {
      int row = idx / (KB / 4);
      int k4 = idx % (KB / 4);
      float4 v = make_float4(0.f, 0.f, 0.f, 0.f);
      if (row0 + row < n)
        v = *(const float4*)(X + (size_t)(row0 + row) * K + k0 + k4 * 4);
      *(float4*)(Xs + row * XS + k4 * 4) = v;
    }
    constexpr int WF4 = KB * F / 4;
    for (int idx = tid; idx < WF4; idx += 256) {
      int wr = idx / (F / 4);
      int wc4 = idx % (F / 4);
      *(float4*)(Ws + wr * F + wc4 * 4) =
          *(const float4*)(W + (size_t)(k0 + wr) * F + wc4 * 4);
    }
    __syncthreads();
#pragma unroll
    for (int kk = 0; kk < KB; kk += 4) {
      float4 xv[RPT];
#pragma unroll
      for (int r = 0; r < RPT; ++r)
        xv[r] = *(const float4*)(Xs + (rg * RPT + r) * XS + kk);
#pragma unroll
      for (int j = 0; j < 4; ++j) {
        float4 w = *(const float4*)(Ws + (kk + j) * F + cg * 4);
#pragma unroll
        for (int r = 0; r < RPT; ++r) {
          float xval = (j == 0) ? xv[r].x : (j == 1) ? xv[r].y : (j == 2) ? xv[r].z : xv[r].w;
          acc[r].x = fmaf(xval, w.x, acc[r].x);
          acc[r].y = fmaf(xval, w.y, acc[r].y);
          acc[r].z = fmaf(xval, w.z, acc[r].z);
          acc[r].w = fmaf(xval, w.w, acc[r].w);
        }
      }
    }
  }
#pragma unroll
  for (int r = 0; r < RPT; ++r) {
    int row = row0 + rg * RPT + r;
    if (row < n) {
      float s = dinv[row];
      ushort4 o;
      o.x = f2bf(s * acc[r].x);
      o.y = f2bf(s * acc[r].y);
      o.z = f2bf(s * acc[r].z);
      o.w = f2bf(s * acc[r].w);
      *(ushort4*)(C + (size_t)row * F + cg * 4) = o;
    }
  }
}

// ---------- CSR SpMM: out[d] = dinv[d]*(t'[d] + sum_c t'[c]) + b, opt ReLU ----------
// t' rows bf16, pre-scaled by dinv[row]. TWO destination nodes per wave (MLP).

template <int F, bool RELU>
__global__ __launch_bounds__(256) void spmm_kernel(const ushort_t* __restrict__ t,
    const int* __restrict__ row_start, const int* __restrict__ deg,
    const int* __restrict__ col, const float* __restrict__ dinv,
    const float* __restrict__ bias, float* __restrict__ out, int n) {
  int gw = (int)((blockIdx.x * 256u + threadIdx.x) >> 6);
  int lane = threadIdx.x & 63;
  int n0 = gw * 2;
  int n1 = n0 + 1;
  if (n0 >= n) return;
  bool h1 = (n1 < n);
  int rs0 = row_start[n0], e0 = deg[n0] - 1;
  int rs1 = h1 ? row_start[n1] : 0, e1 = h1 ? (deg[n1] - 1) : 0;
  float di0 = dinv[n0];
  float di1 = h1 ? dinv[n1] : 0.f;

  if constexpr (F == 128) {
    uint_t s0 = ((const uint_t*)(t + (size_t)n0 * F))[lane];
    float ax0 = bf2f((ushort_t)(s0 & 0xFFFF)), ay0 = bf2f((ushort_t)(s0 >> 16));
    float ax1 = 0.f, ay1 = 0.f;
    if (h1) {
      uint_t s1 = ((const uint_t*)(t + (size_t)n1 * F))[lane];
      ax1 = bf2f((ushort_t)(s1 & 0xFFFF)); ay1 = bf2f((ushort_t)(s1 >> 16));
    }
    int p0 = rs0, q0 = rs0 + e0;
    int p1 = rs1, q1 = rs1 + e1;
    // dual-stream main loop: 8 gathers in flight
    while (p0 + 4 <= q0 && p1 + 4 <= q1) {
      int c[8];
      uint_t v[8];
#pragma unroll
      for (int j = 0; j < 4; ++j) { c[j] = col[p0 + j]; c[4 + j] = col[p1 + j]; }
#pragma unroll
      for (int j = 0; j < 8; ++j) v[j] = ((const uint_t*)(t + (size_t)c[j] * F))[lane];
#pragma unroll
      for (int j = 0; j < 4; ++j) {
        ax0 += bf2f((ushort_t)(v[j] & 0xFFFF));
        ay0 += bf2f((ushort_t)(v[j] >> 16));
        ax1 += bf2f((ushort_t)(v[4 + j] & 0xFFFF));
        ay1 += bf2f((ushort_t)(v[4 + j] >> 16));
      }
      p0 += 4; p1 += 4;
    }
    // tails (unroll 4 then scalar)
    for (; p0 + 4 <= q0; p0 += 4) {
      int c[4]; uint_t v[4];
#pragma unroll
      for (int j = 0; j < 4; ++j) c[j] = col[p0 + j];
#pragma unroll
      for (int j = 0; j < 4; ++j) v[j] = ((const uint_t*)(t + (size_t)c[j] * F))[lane];
#pragma unroll
      for (int j = 0; j < 4; ++j) {
        ax0 += bf2f((ushort_t)(v[j] & 0xFFFF)); ay0 += bf2f((ushort_t)(v[j] >> 16));
      }
    }
    for (; p0 < q0; ++p0) {
      uint_t v = ((const uint_t*)(t + (size_t)col[p0] * F))[lane];
      ax0 += bf2f((ushort_t)(v & 0xFFFF)); ay0 += bf2f((ushort_t)(v >> 16));
    }
    for (; p1 + 4 <= q1; p1 += 4) {
      int c[4]; uint_t v[4];
#pragma unroll
      for (int j = 0; j < 4; ++j) c[j] = col[p1 + j];
#pragma unroll
      for (int j = 0; j < 4; ++j) v[j] = ((const uint_t*)(t + (size_t)c[j] * F))[lane];
#pragma unroll
      for (int j = 0; j < 4; ++j) {
        ax1 += bf2f((ushort_t)(v[j] & 0xFFFF)); ay1 += bf2f((ushort_t)(v[j] >> 16));
      }
    }
    for (; p1 < q1; ++p1) {
      uint_t v = ((const uint_t*)(t + (size_t)col[p1] * F))[lane];
      ax1 += bf2f((ushort_t)(v & 0xFFFF)); ay1 += bf2f((ushort_t)(v >> 16));
    }
    float bx = bias[2 * lane], by = bias[2 * lane + 1];
    ax0 = fmaf(di0, ax0, bx); ay0 = fmaf(di0, ay0, by);
    if constexpr (RELU) { ax0 = fmaxf(ax0, 0.f); ay0 = fmaxf(ay0, 0.f); }
    float2 o0; o0.x = ax0; o0.y = ay0;
    ((float2*)(out + (size_t)n0 * F))[lane] = o0;
    if (h1) {
      ax1 = fmaf(di1, ax1, bx); ay1 = fmaf(di1, ay1, by);
      if constexpr (RELU) { ax1 = fmaxf(ax1, 0.f); ay1 = fmaxf(ay1, 0.f); }
      float2 o1; o1.x = ax1; o1.y = ay1;
      ((float2*)(out + (size_t)n1 * F))[lane] = o1;
    }
  } else {  // F == 64: one bf16 per lane
    float a0 = bf2f(t[(size_t)n0 * F + lane]);
    float a1 = h1 ? bf2f(t[(size_t)n1 * F + lane]) : 0.f;
    int p0 = rs0, q0 = rs0 + e0;
    int p1 = rs1, q1 = rs1 + e1;
    while (p0 + 4 <= q0 && p1 + 4 <= q1) {
      int c[8];
      ushort_t v[8];
#pragma unroll
      for (int j = 0; j < 4; ++j) { c[j] = col[p0 + j]; c[4 + j] = col[p1 + j]; }
#pragma unroll
      for (int j = 0; j < 8; ++j) v[j] = t[(size_t)c[j] * F + lane];
#pragma unroll
      for (int j = 0; j < 4; ++j) { a0 += bf2f(v[j]); a1 += bf2f(v[4 + j]); }
      p0 += 4; p1 += 4;
    }
    for (; p0 + 4 <= q0; p0 += 4) {
      int c[4]; ushort_t v[4];
#pragma unroll
      for (int j = 0; j < 4; ++j) c[j] = col[p0 + j];
#pragma unroll
      for (int j = 0; j < 4; ++j) v[j] = t[(size_t)c[j] * F + lane];
#pragma unroll
      for (int j = 0; j < 4; ++j) a0 += bf2f(v[j]);
    }
    for (; p0 < q0; ++p0) a0 += bf2f(t[(size_t)col[p0] * F + lane]);
    for (; p1 + 4 <= q1; p1 += 4) {
      int c[4]; ushort_t v[4];
#pragma unroll
      for (int j = 0; j < 4; ++j) c[j] = col[p1 + j];
#pragma unroll
      for (int j = 0; j < 4; ++j) v[j] = t[(size_t)c[j] * F + lane];
#pragma unroll
      for (int j = 0; j < 4; ++j) a1 += bf2f(v[j]);
    }
    for (; p1 < q1; ++p1) a1 += bf2f(t[(size_t)col[p1] * F + lane]);
    float b = bias[lane];
    a0 = fmaf(di0, a0, b);
    if constexpr (RELU) a0 = fmaxf(a0, 0.f);
    out[(size_t)n0 * F + lane] = a0;
    if (h1) {
      a1 = fmaf(di1, a1, b);
      if constexpr (RELU) a1 = fmaxf(a1, 0.f);
      out[(size_t)n1 * F + lane] = a1;
    }
  }
}

// ---------- launch ----------

extern "C" void kernel_launch(void* const* d_in, const int* in_sizes, int n_in,
                              void* d_out, int out_size, void* d_ws, size_t ws_size,
                              hipStream_t stream) {
  const float* x  = (const float*)d_in[0];
  const float* W1 = (const float*)d_in[1];
  const float* b1 = (const float*)d_in[2];
  const float* W2 = (const float*)d_in[3];
  const float* b2 = (const float*)d_in[4];
  const float* W3 = (const float*)d_in[5];
  const float* b3 = (const float*)d_in[6];
  const int* ei   = (const int*)d_in[7];  // harness delivers integers as int32

  int n = in_sizes[0] / DIN;
  int e = in_sizes[7] / 2;
  const int* src = ei;
  const int* dst = ei + e;

  char* ws = (char*)d_ws;
  size_t off = 0;
  auto alloc = [&](size_t bytes) -> void* {
    off = (off + 255) & ~(size_t)255;
    void* p = ws + off;
    off += bytes;
    return p;
  };
  int nscan = (n + 1023) / 1024;
  int*      c0        = (int*)alloc((size_t)n * 4);
  int*      c1        = (int*)alloc((size_t)n * 4);
  int*      c2        = (int*)alloc((size_t)n * 4);
  int*      c3        = (int*)alloc((size_t)n * 4);
  int*      deg       = (int*)alloc((size_t)n * 4);
  float*    dinv      = (float*)alloc((size_t)n * 4);
  int*      row_start = (int*)alloc((size_t)n * 4);
  int4*     sub       = (int4*)alloc((size_t)n * 16);
  int*      blocksum  = (int*)alloc((size_t)nscan * 4);
  int*      slot      = (int*)alloc((size_t)e * 4);
  int*      col       = (int*)alloc((size_t)e * 4);
  ushort_t* T         = (ushort_t*)alloc((size_t)n * HID * 2);  // bf16 GEMM out
  float*    Hf        = (float*)alloc((size_t)n * HID * 4);     // fp32 SpMM out
  (void)ws_size;

  int nb256 = (n + 255) / 256;
  int eb256 = (e + 255) / 256;
  int gemm_blocks = (n + 63) / 64;
  int nwaves = (n + 1) / 2;                 // 2 nodes per wave
  int spmm_blocks = (nwaves + 3) / 4;       // 4 waves per block

  init_deg_kernel<<<nb256, 256, 0, stream>>>(c0, c1, c2, c3, n);
  deg_slot_kernel<<<eb256, 256, 0, stream>>>(dst, c0, c1, c2, c3, slot, e);
  scanA_kernel<<<nscan, 256, 0, stream>>>(c0, c1, c2, c3, blocksum, n);
  scanB_kernel<<<1, 64, 0, stream>>>(blocksum, nscan);
  scanC_kernel<<<nscan, 256, 0, stream>>>(c0, c1, c2, c3, blocksum, row_start, deg, dinv, sub, n);
  fill_kernel<<<eb256, 256, 0, stream>>>(src, dst, slot, sub, col, e);

  gemm_kernel<DIN, HID><<<gemm_blocks, 256, 0, stream>>>(x, W1, dinv, T, n);
  spmm_kernel<HID, true><<<spmm_blocks, 256, 0, stream>>>(T, row_start, deg, col, dinv, b1, Hf, n);
  gemm_kernel<HID, HID><<<gemm_blocks, 256, 0, stream>>>(Hf, W2, dinv, T, n);
  spmm_kernel<HID, true><<<spmm_blocks, 256, 0, stream>>>(T, row_start, deg, col, dinv, b2, Hf, n);
  gemm_kernel<HID, DOUT><<<gemm_blocks, 256, 0, stream>>>(Hf, W3, dinv, T, n);
  spmm_kernel<DOUT, false><<<spmm_blocks, 256, 0, stream>>>(T, row_start, deg, col, dinv, b3, (float*)d_out, n);
}

// Round 8
// 414.935 us; speedup vs baseline: 1.9855x; 1.0927x over previous
//
#include <hip/hip_runtime.h>

// GCN 3-layer: N=50000, E=1.6M, D_IN=256, H=128, D_OUT=64, fp32 in/out.
// CSR build: 4-way split-atomic degree pass (atomic return = slot), parallel
// scan with per-node int4 sub-base table, atomic-free scatter fill.
// Per layer: split-bf16 MFMA GEMM (A=fp32 split hi/lo in-register, W prepped
// hi/lo fragment-ready; 3 mfma passes ~ fp32 accuracy) writing bf16 rows
// pre-scaled by dinv[row] -> CSR-SpMM summing gathered bf16 rows.

constexpr int DIN = 256;
constexpr int HID = 128;
constexpr int DOUT = 64;

typedef unsigned short ushort_t;
typedef unsigned int uint_t;
typedef __attribute__((ext_vector_type(8))) short bf16x8;
typedef __attribute__((ext_vector_type(4))) float f32x4;

__device__ inline ushort_t f2bf(float f) {
  uint_t u = __float_as_uint(f);
  u += 0x7FFF + ((u >> 16) & 1);  // RNE
  return (ushort_t)(u >> 16);
}
__device__ inline float bf2f(ushort_t b) {
  return __uint_as_float(((uint_t)b) << 16);
}

// ---------- degree + slot (single atomic pass, 4-way split counters) ----------

__global__ void init_deg_kernel(int* __restrict__ c0, int* __restrict__ c1,
                                int* __restrict__ c2, int* __restrict__ c3, int n) {
  int i = blockIdx.x * blockDim.x + threadIdx.x;
  if (i < n) { c0[i] = 1; c1[i] = 0; c2[i] = 0; c3[i] = 0; }  // self-loop in c0
}

__global__ void deg_slot_kernel(const int* __restrict__ dst, int* __restrict__ c0,
                                int* __restrict__ c1, int* __restrict__ c2,
                                int* __restrict__ c3, int* __restrict__ slot, int e) {
  int i = blockIdx.x * blockDim.x + threadIdx.x;
  if (i >= e) return;
  int d = dst[i];
  int k = i & 3;
  int s;
  if      (k == 0) s = atomicAdd(&c0[d], 1);  // >= 1
  else if (k == 1) s = atomicAdd(&c1[d], 1);  // >= 0
  else if (k == 2) s = atomicAdd(&c2[d], 1);
  else             s = atomicAdd(&c3[d], 1);
  slot[i] = s;
}

// ---------- 3-phase exclusive scan of (deg-1), 1024 elems / block ----------

__global__ __launch_bounds__(256) void scanA_kernel(const int* __restrict__ c0,
    const int* __restrict__ c1, const int* __restrict__ c2, const int* __restrict__ c3,
    int* __restrict__ blocksum, int n) {
  __shared__ int sums[256];
  int t = threadIdx.x;
  int base = blockIdx.x * 1024 + t * 4;
  int local = 0;
#pragma unroll
  for (int k = 0; k < 4; ++k) {
    int i = base + k;
    if (i < n) local += c0[i] + c1[i] + c2[i] + c3[i] - 1;
  }
  sums[t] = local;
  __syncthreads();
  for (int off = 128; off > 0; off >>= 1) {
    if (t < off) sums[t] += sums[t + off];
    __syncthreads();
  }
  if (t == 0) blocksum[blockIdx.x] = sums[0];
}

__global__ __launch_bounds__(64) void scanB_kernel(int* __restrict__ blocksum, int nb) {
  int lane = threadIdx.x;
  int carry = 0;
  for (int base = 0; base < nb; base += 64) {
    int i = base + lane;
    int orig = (i < nb) ? blocksum[i] : 0;
    int v = orig;
#pragma unroll
    for (int off = 1; off < 64; off <<= 1) {
      int u = __shfl_up(v, off, 64);
      if (lane >= off) v += u;
    }
    int total = __shfl(v, 63, 64);
    if (i < nb) blocksum[i] = carry + v - orig;  // exclusive
    carry += total;
  }
}

// Phase C: row_start/deg/dinv + int4 sub-base table for the 4 slot classes.
__global__ __launch_bounds__(256) void scanC_kernel(const int* __restrict__ c0,
    const int* __restrict__ c1, const int* __restrict__ c2, const int* __restrict__ c3,
    const int* __restrict__ blocksum, int* __restrict__ row_start, int* __restrict__ deg,
    float* __restrict__ dinv, int4* __restrict__ sub, int n) {
  __shared__ int sums[256];
  int t = threadIdx.x;
  int base = blockIdx.x * 1024 + t * 4;
  int d[4], k0[4], k1[4], k2[4];
  int local = 0;
#pragma unroll
  for (int k = 0; k < 4; ++k) {
    int i = base + k;
    if (i < n) {
      k0[k] = c0[i]; k1[k] = c1[i]; k2[k] = c2[i];
      d[k] = k0[k] + k1[k] + k2[k] + c3[i];
      local += d[k] - 1;
    } else { d[k] = 1; k0[k] = 1; k1[k] = 0; k2[k] = 0; }
  }
  sums[t] = local;
  __syncthreads();
  for (int off = 1; off < 256; off <<= 1) {
    int v = (t >= off) ? sums[t - off] : 0;
    __syncthreads();
    sums[t] += v;
    __syncthreads();
  }
  int run = blocksum[blockIdx.x] + sums[t] - local;  // exclusive offset
#pragma unroll
  for (int k = 0; k < 4; ++k) {
    int i = base + k;
    if (i < n) {
      row_start[i] = run;
      deg[i] = d[k];
      dinv[i] = rsqrtf((float)d[k]);
      int4 sb;
      sb.x = run - 1;                  // class 0: slot >= 1 -> pos = run-1+slot
      sb.y = run + (k0[k] - 1);        // class 1: slot >= 0
      sb.z = sb.y + k1[k];             // class 2
      sb.w = sb.z + k2[k];             // class 3
      sub[i] = sb;
      run += d[k] - 1;
    }
  }
}

// ---------- CSR fill: atomic-free scatter, one int4 gather per edge ----------

__global__ void fill_kernel(const int* __restrict__ src, const int* __restrict__ dst,
    const int* __restrict__ slot, const int4* __restrict__ sub,
    int* __restrict__ col, int e) {
  int i = blockIdx.x * blockDim.x + threadIdx.x;
  if (i >= e) return;
  int d = dst[i];
  int k = i & 3;
  int4 sb = sub[d];
  int base = (k == 0) ? sb.x : (k == 1) ? sb.y : (k == 2) ? sb.z : sb.w;
  col[base + slot[i]] = src[i];
}

// ---------- weight prep: W[K][F] fp32 -> fragment-ready bf16 hi/lo ----------
// Layout: Bp[t = n/16][s = k/32][lane = (k/8 % 4)*16 + n%16][j = k%8]

__global__ void wprep_kernel(const float* __restrict__ W, ushort_t* __restrict__ Bhi,
                             ushort_t* __restrict__ Blo, int K, int F) {
  int i = blockIdx.x * blockDim.x + threadIdx.x;
  if (i >= K * F) return;
  int k = i / F, nn = i % F;
  int t = nn >> 4, s = k >> 5, q = (k >> 3) & 3, j = k & 7;
  int lane = q * 16 + (nn & 15);
  int KS = K >> 5;
  size_t idx = (((size_t)t * KS + s) * 64 + (size_t)lane) * 8 + j;
  float w = W[i];
  ushort_t h = f2bf(w);
  float r = w - bf2f(h);
  Bhi[idx] = h;
  Blo[idx] = f2bf(r);
}

// ---------- split-bf16 MFMA GEMM: T[n,F] = bf16(dinv[row] * (X[n,K] @ W[K,F])) ----
// 256 threads = 4 waves; block covers 64 rows; wave w covers rows +16w..+16w+15.
// A frag (16x32 tile): lane holds A[m=lane&15][k=s*32 + (lane>>4)*8 + j], fp32
// loaded and split hi/lo in-register. B frags from prepped arrays (L1-resident).
// acc = Ahi*Bhi + Alo*Bhi + Ahi*Blo (fp32 accum; lo*lo dropped, ~2^-18 rel).

template <int K, int F>
__global__ __launch_bounds__(256) void gemm_mfma_kernel(const float* __restrict__ X,
    const ushort_t* __restrict__ Bhi, const ushort_t* __restrict__ Blo,
    const float* __restrict__ dinv, ushort_t* __restrict__ T, int n) {
  constexpr int NT = F / 16;   // n-tiles
  constexpr int KS = K / 32;   // k-steps
  int wave = threadIdx.x >> 6;
  int lane = threadIdx.x & 63;
  int q = lane >> 4;
  int m = lane & 15;
  int arow = blockIdx.x * 64 + wave * 16 + m;
  bool valid = arow < n;
  const float* xrow = X + (size_t)arow * K;

  f32x4 acc[NT];
#pragma unroll
  for (int t = 0; t < NT; ++t) acc[t] = (f32x4){0.f, 0.f, 0.f, 0.f};

  for (int s = 0; s < KS; ++s) {
    float av[8];
    if (valid) {
      float4 u0 = *(const float4*)(xrow + s * 32 + q * 8);
      float4 u1 = *(const float4*)(xrow + s * 32 + q * 8 + 4);
      av[0] = u0.x; av[1] = u0.y; av[2] = u0.z; av[3] = u0.w;
      av[4] = u1.x; av[5] = u1.y; av[6] = u1.z; av[7] = u1.w;
    } else {
#pragma unroll
      for (int j = 0; j < 8; ++j) av[j] = 0.f;
    }
    bf16x8 ahi, alo;
#pragma unroll
    for (int j = 0; j < 8; ++j) {
      ushort_t h = f2bf(av[j]);
      ahi[j] = (short)h;
      alo[j] = (short)f2bf(av[j] - bf2f(h));
    }
#pragma unroll
    for (int t = 0; t < NT; ++t) {
      size_t boff = (((size_t)t * KS + s) * 64 + (size_t)lane) * 8;
      bf16x8 bh = *(const bf16x8*)(Bhi + boff);
      bf16x8 bl = *(const bf16x8*)(Blo + boff);
      acc[t] = __builtin_amdgcn_mfma_f32_16x16x32_bf16(ahi, bh, acc[t], 0, 0, 0);
      acc[t] = __builtin_amdgcn_mfma_f32_16x16x32_bf16(alo, bh, acc[t], 0, 0, 0);
      acc[t] = __builtin_amdgcn_mfma_f32_16x16x32_bf16(ahi, bl, acc[t], 0, 0, 0);
    }
  }

  // Epilogue: D[row = q*4 + r][col = m] per tile; scale by dinv, cast bf16.
  int orow_base = blockIdx.x * 64 + wave * 16 + q * 4;
#pragma unroll
  for (int r = 0; r < 4; ++r) {
    int orow = orow_base + r;
    if (orow >= n) continue;
    float sc = dinv[orow];
    ushort_t* trow = T + (size_t)orow * F + m;
#pragma unroll
    for (int t = 0; t < NT; ++t) trow[t * 16] = f2bf(sc * acc[t][r]);
  }
}

// ---------- CSR SpMM: out[d] = dinv[d]*(t'[d] + sum_c t'[c]) + b, opt ReLU ----------
// t' rows bf16, pre-scaled by dinv[row]. TWO destination nodes per wave (MLP).

template <int F, bool RELU>
__global__ __launch_bounds__(256) void spmm_kernel(const ushort_t* __restrict__ t,
    const int* __restrict__ row_start, const int* __restrict__ deg,
    const int* __restrict__ col, const float* __restrict__ dinv,
    const float* __restrict__ bias, float* __restrict__ out, int n) {
  int gw = (int)((blockIdx.x * 256u + threadIdx.x) >> 6);
  int lane = threadIdx.x & 63;
  int n0 = gw * 2;
  int n1 = n0 + 1;
  if (n0 >= n) return;
  bool h1 = (n1 < n);
  int rs0 = row_start[n0], e0 = deg[n0] - 1;
  int rs1 = h1 ? row_start[n1] : 0, e1 = h1 ? (deg[n1] - 1) : 0;
  float di0 = dinv[n0];
  float di1 = h1 ? dinv[n1] : 0.f;

  if constexpr (F == 128) {
    uint_t s0 = ((const uint_t*)(t + (size_t)n0 * F))[lane];
    float ax0 = bf2f((ushort_t)(s0 & 0xFFFF)), ay0 = bf2f((ushort_t)(s0 >> 16));
    float ax1 = 0.f, ay1 = 0.f;
    if (h1) {
      uint_t s1 = ((const uint_t*)(t + (size_t)n1 * F))[lane];
      ax1 = bf2f((ushort_t)(s1 & 0xFFFF)); ay1 = bf2f((ushort_t)(s1 >> 16));
    }
    int p0 = rs0, q0 = rs0 + e0;
    int p1 = rs1, q1 = rs1 + e1;
    while (p0 + 4 <= q0 && p1 + 4 <= q1) {
      int c[8];
      uint_t v[8];
#pragma unroll
      for (int j = 0; j < 4; ++j) { c[j] = col[p0 + j]; c[4 + j] = col[p1 + j]; }
#pragma unroll
      for (int j = 0; j < 8; ++j) v[j] = ((const uint_t*)(t + (size_t)c[j] * F))[lane];
#pragma unroll
      for (int j = 0; j < 4; ++j) {
        ax0 += bf2f((ushort_t)(v[j] & 0xFFFF));
        ay0 += bf2f((ushort_t)(v[j] >> 16));
        ax1 += bf2f((ushort_t)(v[4 + j] & 0xFFFF));
        ay1 += bf2f((ushort_t)(v[4 + j] >> 16));
      }
      p0 += 4; p1 += 4;
    }
    for (; p0 + 4 <= q0; p0 += 4) {
      int c[4]; uint_t v[4];
#pragma unroll
      for (int j = 0; j < 4; ++j) c[j] = col[p0 + j];
#pragma unroll
      for (int j = 0; j < 4; ++j) v[j] = ((const uint_t*)(t + (size_t)c[j] * F))[lane];
#pragma unroll
      for (int j = 0; j < 4; ++j) {
        ax0 += bf2f((ushort_t)(v[j] & 0xFFFF)); ay0 += bf2f((ushort_t)(v[j] >> 16));
      }
    }
    for (; p0 < q0; ++p0) {
      uint_t v = ((const uint_t*)(t + (size_t)col[p0] * F))[lane];
      ax0 += bf2f((ushort_t)(v & 0xFFFF)); ay0 += bf2f((ushort_t)(v >> 16));
    }
    for (; p1 + 4 <= q1; p1 += 4) {
      int c[4]; uint_t v[4];
#pragma unroll
      for (int j = 0; j < 4; ++j) c[j] = col[p1 + j];
#pragma unroll
      for (int j = 0; j < 4; ++j) v[j] = ((const uint_t*)(t + (size_t)c[j] * F))[lane];
#pragma unroll
      for (int j = 0; j < 4; ++j) {
        ax1 += bf2f((ushort_t)(v[j] & 0xFFFF)); ay1 += bf2f((ushort_t)(v[j] >> 16));
      }
    }
    for (; p1 < q1; ++p1) {
      uint_t v = ((const uint_t*)(t + (size_t)col[p1] * F))[lane];
      ax1 += bf2f((ushort_t)(v & 0xFFFF)); ay1 += bf2f((ushort_t)(v >> 16));
    }
    float bx = bias[2 * lane], by = bias[2 * lane + 1];
    ax0 = fmaf(di0, ax0, bx); ay0 = fmaf(di0, ay0, by);
    if constexpr (RELU) { ax0 = fmaxf(ax0, 0.f); ay0 = fmaxf(ay0, 0.f); }
    float2 o0; o0.x = ax0; o0.y = ay0;
    ((float2*)(out + (size_t)n0 * F))[lane] = o0;
    if (h1) {
      ax1 = fmaf(di1, ax1, bx); ay1 = fmaf(di1, ay1, by);
      if constexpr (RELU) { ax1 = fmaxf(ax1, 0.f); ay1 = fmaxf(ay1, 0.f); }
      float2 o1; o1.x = ax1; o1.y = ay1;
      ((float2*)(out + (size_t)n1 * F))[lane] = o1;
    }
  } else {  // F == 64: one bf16 per lane
    float a0 = bf2f(t[(size_t)n0 * F + lane]);
    float a1 = h1 ? bf2f(t[(size_t)n1 * F + lane]) : 0.f;
    int p0 = rs0, q0 = rs0 + e0;
    int p1 = rs1, q1 = rs1 + e1;
    while (p0 + 4 <= q0 && p1 + 4 <= q1) {
      int c[8];
      ushort_t v[8];
#pragma unroll
      for (int j = 0; j < 4; ++j) { c[j] = col[p0 + j]; c[4 + j] = col[p1 + j]; }
#pragma unroll
      for (int j = 0; j < 8; ++j) v[j] = t[(size_t)c[j] * F + lane];
#pragma unroll
      for (int j = 0; j < 4; ++j) { a0 += bf2f(v[j]); a1 += bf2f(v[4 + j]); }
      p0 += 4; p1 += 4;
    }
    for (; p0 + 4 <= q0; p0 += 4) {
      int c[4]; ushort_t v[4];
#pragma unroll
      for (int j = 0; j < 4; ++j) c[j] = col[p0 + j];
#pragma unroll
      for (int j = 0; j < 4; ++j) v[j] = t[(size_t)c[j] * F + lane];
#pragma unroll
      for (int j = 0; j < 4; ++j) a0 += bf2f(v[j]);
    }
    for (; p0 < q0; ++p0) a0 += bf2f(t[(size_t)col[p0] * F + lane]);
    for (; p1 + 4 <= q1; p1 += 4) {
      int c[4]; ushort_t v[4];
#pragma unroll
      for (int j = 0; j < 4; ++j) c[j] = col[p1 + j];
#pragma unroll
      for (int j = 0; j < 4; ++j) v[j] = t[(size_t)c[j] * F + lane];
#pragma unroll
      for (int j = 0; j < 4; ++j) a1 += bf2f(v[j]);
    }
    for (; p1 < q1; ++p1) a1 += bf2f(t[(size_t)col[p1] * F + lane]);
    float b = bias[lane];
    a0 = fmaf(di0, a0, b);
    if constexpr (RELU) a0 = fmaxf(a0, 0.f);
    out[(size_t)n0 * F + lane] = a0;
    if (h1) {
      a1 = fmaf(di1, a1, b);
      if constexpr (RELU) a1 = fmaxf(a1, 0.f);
      out[(size_t)n1 * F + lane] = a1;
    }
  }
}

// ---------- launch ----------

extern "C" void kernel_launch(void* const* d_in, const int* in_sizes, int n_in,
                              void* d_out, int out_size, void* d_ws, size_t ws_size,
                              hipStream_t stream) {
  const float* x  = (const float*)d_in[0];
  const float* W1 = (const float*)d_in[1];
  const float* b1 = (const float*)d_in[2];
  const float* W2 = (const float*)d_in[3];
  const float* b2 = (const float*)d_in[4];
  const float* W3 = (const float*)d_in[5];
  const float* b3 = (const float*)d_in[6];
  const int* ei   = (const int*)d_in[7];  // harness delivers integers as int32

  int n = in_sizes[0] / DIN;
  int e = in_sizes[7] / 2;
  const int* src = ei;
  const int* dst = ei + e;

  char* ws = (char*)d_ws;
  size_t off = 0;
  auto alloc = [&](size_t bytes) -> void* {
    off = (off + 255) & ~(size_t)255;
    void* p = ws + off;
    off += bytes;
    return p;
  };
  int nscan = (n + 1023) / 1024;
  int*      c0        = (int*)alloc((size_t)n * 4);
  int*      c1        = (int*)alloc((size_t)n * 4);
  int*      c2        = (int*)alloc((size_t)n * 4);
  int*      c3        = (int*)alloc((size_t)n * 4);
  int*      deg       = (int*)alloc((size_t)n * 4);
  float*    dinv      = (float*)alloc((size_t)n * 4);
  int*      row_start = (int*)alloc((size_t)n * 4);
  int4*     sub       = (int4*)alloc((size_t)n * 16);
  int*      blocksum  = (int*)alloc((size_t)nscan * 4);
  int*      slot      = (int*)alloc((size_t)e * 4);
  int*      col       = (int*)alloc((size_t)e * 4);
  ushort_t* T         = (ushort_t*)alloc((size_t)n * HID * 2);  // bf16 GEMM out
  float*    Hf        = (float*)alloc((size_t)n * HID * 4);     // fp32 SpMM out
  ushort_t* W1hi      = (ushort_t*)alloc((size_t)DIN * HID * 2);
  ushort_t* W1lo      = (ushort_t*)alloc((size_t)DIN * HID * 2);
  ushort_t* W2hi      = (ushort_t*)alloc((size_t)HID * HID * 2);
  ushort_t* W2lo      = (ushort_t*)alloc((size_t)HID * HID * 2);
  ushort_t* W3hi      = (ushort_t*)alloc((size_t)HID * DOUT * 2);
  ushort_t* W3lo      = (ushort_t*)alloc((size_t)HID * DOUT * 2);
  (void)ws_size;

  int nb256 = (n + 255) / 256;
  int eb256 = (e + 255) / 256;
  int gemm_blocks = (n + 63) / 64;
  int nwaves = (n + 1) / 2;                 // 2 nodes per wave
  int spmm_blocks = (nwaves + 3) / 4;       // 4 waves per block

  init_deg_kernel<<<nb256, 256, 0, stream>>>(c0, c1, c2, c3, n);
  deg_slot_kernel<<<eb256, 256, 0, stream>>>(dst, c0, c1, c2, c3, slot, e);
  scanA_kernel<<<nscan, 256, 0, stream>>>(c0, c1, c2, c3, blocksum, n);
  scanB_kernel<<<1, 64, 0, stream>>>(blocksum, nscan);
  scanC_kernel<<<nscan, 256, 0, stream>>>(c0, c1, c2, c3, blocksum, row_start, deg, dinv, sub, n);
  fill_kernel<<<eb256, 256, 0, stream>>>(src, dst, slot, sub, col, e);

  wprep_kernel<<<(DIN * HID + 255) / 256, 256, 0, stream>>>(W1, W1hi, W1lo, DIN, HID);
  wprep_kernel<<<(HID * HID + 255) / 256, 256, 0, stream>>>(W2, W2hi, W2lo, HID, HID);
  wprep_kernel<<<(HID * DOUT + 255) / 256, 256, 0, stream>>>(W3, W3hi, W3lo, HID, DOUT);

  gemm_mfma_kernel<DIN, HID><<<gemm_blocks, 256, 0, stream>>>(x, W1hi, W1lo, dinv, T, n);
  spmm_kernel<HID, true><<<spmm_blocks, 256, 0, stream>>>(T, row_start, deg, col, dinv, b1, Hf, n);
  gemm_mfma_kernel<HID, HID><<<gemm_blocks, 256, 0, stream>>>(Hf, W2hi, W2lo, dinv, T, n);
  spmm_kernel<HID, true><<<spmm_blocks, 256, 0, stream>>>(T, row_start, deg, col, dinv, b2, Hf, n);
  gemm_mfma_kernel<HID, DOUT><<<gemm_blocks, 256, 0, stream>>>(Hf, W3hi, W3lo, dinv, T, n);
  spmm_kernel<DOUT, false><<<spmm_blocks, 256, 0, stream>>>(T, row_start, deg, col, dinv, b3, (float*)d_out, n);
}

// Round 9
// 412.585 us; speedup vs baseline: 1.9968x; 1.0057x over previous
//
#include <hip/hip_runtime.h>

// GCN 3-layer: N=50000, E=1.6M, D_IN=256, H=128, D_OUT=64, fp32 in/out.
// CSR build: 4-way split-atomic degree pass (atomic return = slot), parallel
// scan with per-node int4 sub-base table, atomic-free scatter fill.
// Per layer: split-bf16 MFMA GEMM -> CSR-SpMM over bf16 rows.
// Round 9: fuse independent launches — [wprep|deg_slot] and [gemm1|fill] —
// so atomic-bound waves (no VALU/MFMA use) overlap with compute waves.

constexpr int DIN = 256;
constexpr int HID = 128;
constexpr int DOUT = 64;

typedef unsigned short ushort_t;
typedef unsigned int uint_t;
typedef __attribute__((ext_vector_type(8))) short bf16x8;
typedef __attribute__((ext_vector_type(4))) float f32x4;

__device__ inline ushort_t f2bf(float f) {
  uint_t u = __float_as_uint(f);
  u += 0x7FFF + ((u >> 16) & 1);  // RNE
  return (ushort_t)(u >> 16);
}
__device__ inline float bf2f(ushort_t b) {
  return __uint_as_float(((uint_t)b) << 16);
}

// ---------- init ----------

__global__ void init_deg_kernel(int* __restrict__ c0, int* __restrict__ c1,
                                int* __restrict__ c2, int* __restrict__ c3, int n) {
  int i = blockIdx.x * blockDim.x + threadIdx.x;
  if (i < n) { c0[i] = 1; c1[i] = 0; c2[i] = 0; c3[i] = 0; }  // self-loop in c0
}

// ---------- weight prep (device fn): W[K][F] fp32 -> fragment bf16 hi/lo ----------
// Layout: Bp[t = n/16][s = k/32][lane = (k/8 % 4)*16 + n%16][j = k%8]

__device__ inline void wprep_one(const float* __restrict__ W, ushort_t* __restrict__ Bhi,
                                 ushort_t* __restrict__ Blo, int K, int F, int i) {
  int k = i / F, nn = i % F;
  int t = nn >> 4, s = k >> 5, q = (k >> 3) & 3, j = k & 7;
  int lane = q * 16 + (nn & 15);
  int KS = K >> 5;
  size_t idx = (((size_t)t * KS + s) * 64 + (size_t)lane) * 8 + j;
  float w = W[i];
  ushort_t h = f2bf(w);
  float r = w - bf2f(h);
  Bhi[idx] = h;
  Blo[idx] = f2bf(r);
}

// ---------- fused A: [wprep x3 | deg_slot] ----------
// wprep blocks first (tiny), then edge-atomic blocks.

__global__ __launch_bounds__(256) void fusedA_kernel(
    const float* __restrict__ W1, ushort_t* __restrict__ W1hi, ushort_t* __restrict__ W1lo,
    const float* __restrict__ W2, ushort_t* __restrict__ W2hi, ushort_t* __restrict__ W2lo,
    const float* __restrict__ W3, ushort_t* __restrict__ W3hi, ushort_t* __restrict__ W3lo,
    const int* __restrict__ dst, int* __restrict__ c0, int* __restrict__ c1,
    int* __restrict__ c2, int* __restrict__ c3, int* __restrict__ slot,
    int e, int wblocks) {
  if ((int)blockIdx.x < wblocks) {
    int idx = blockIdx.x * 256 + threadIdx.x;
    constexpr int S1 = DIN * HID;        // 32768
    constexpr int S2 = S1 + HID * HID;   // 49152
    constexpr int S3 = S2 + HID * DOUT;  // 57344
    if (idx < S1) wprep_one(W1, W1hi, W1lo, DIN, HID, idx);
    else if (idx < S2) wprep_one(W2, W2hi, W2lo, HID, HID, idx - S1);
    else if (idx < S3) wprep_one(W3, W3hi, W3lo, HID, DOUT, idx - S2);
  } else {
    int i = ((int)blockIdx.x - wblocks) * 256 + threadIdx.x;
    if (i >= e) return;
    int d = dst[i];
    int k = i & 3;
    int s;
    if      (k == 0) s = atomicAdd(&c0[d], 1);  // >= 1
    else if (k == 1) s = atomicAdd(&c1[d], 1);  // >= 0
    else if (k == 2) s = atomicAdd(&c2[d], 1);
    else             s = atomicAdd(&c3[d], 1);
    slot[i] = s;
  }
}

// ---------- 3-phase exclusive scan of (deg-1), 1024 elems / block ----------

__global__ __launch_bounds__(256) void scanA_kernel(const int* __restrict__ c0,
    const int* __restrict__ c1, const int* __restrict__ c2, const int* __restrict__ c3,
    int* __restrict__ blocksum, int n) {
  __shared__ int sums[256];
  int t = threadIdx.x;
  int base = blockIdx.x * 1024 + t * 4;
  int local = 0;
#pragma unroll
  for (int k = 0; k < 4; ++k) {
    int i = base + k;
    if (i < n) local += c0[i] + c1[i] + c2[i] + c3[i] - 1;
  }
  sums[t] = local;
  __syncthreads();
  for (int off = 128; off > 0; off >>= 1) {
    if (t < off) sums[t] += sums[t + off];
    __syncthreads();
  }
  if (t == 0) blocksum[blockIdx.x] = sums[0];
}

__global__ __launch_bounds__(64) void scanB_kernel(int* __restrict__ blocksum, int nb) {
  int lane = threadIdx.x;
  int carry = 0;
  for (int base = 0; base < nb; base += 64) {
    int i = base + lane;
    int orig = (i < nb) ? blocksum[i] : 0;
    int v = orig;
#pragma unroll
    for (int off = 1; off < 64; off <<= 1) {
      int u = __shfl_up(v, off, 64);
      if (lane >= off) v += u;
    }
    int total = __shfl(v, 63, 64);
    if (i < nb) blocksum[i] = carry + v - orig;  // exclusive
    carry += total;
  }
}

__global__ __launch_bounds__(256) void scanC_kernel(const int* __restrict__ c0,
    const int* __restrict__ c1, const int* __restrict__ c2, const int* __restrict__ c3,
    const int* __restrict__ blocksum, int* __restrict__ row_start, int* __restrict__ deg,
    float* __restrict__ dinv, int4* __restrict__ sub, int n) {
  __shared__ int sums[256];
  int t = threadIdx.x;
  int base = blockIdx.x * 1024 + t * 4;
  int d[4], k0[4], k1[4], k2[4];
  int local = 0;
#pragma unroll
  for (int k = 0; k < 4; ++k) {
    int i = base + k;
    if (i < n) {
      k0[k] = c0[i]; k1[k] = c1[i]; k2[k] = c2[i];
      d[k] = k0[k] + k1[k] + k2[k] + c3[i];
      local += d[k] - 1;
    } else { d[k] = 1; k0[k] = 1; k1[k] = 0; k2[k] = 0; }
  }
  sums[t] = local;
  __syncthreads();
  for (int off = 1; off < 256; off <<= 1) {
    int v = (t >= off) ? sums[t - off] : 0;
    __syncthreads();
    sums[t] += v;
    __syncthreads();
  }
  int run = blocksum[blockIdx.x] + sums[t] - local;  // exclusive offset
#pragma unroll
  for (int k = 0; k < 4; ++k) {
    int i = base + k;
    if (i < n) {
      row_start[i] = run;
      deg[i] = d[k];
      dinv[i] = rsqrtf((float)d[k]);
      int4 sb;
      sb.x = run - 1;                  // class 0: slot >= 1 -> pos = run-1+slot
      sb.y = run + (k0[k] - 1);        // class 1: slot >= 0
      sb.z = sb.y + k1[k];             // class 2
      sb.w = sb.z + k2[k];             // class 3
      sub[i] = sb;
      run += d[k] - 1;
    }
  }
}

// ---------- split-bf16 MFMA GEMM (device fn) ----------
// 256 threads = 4 waves; covers 64 rows per block-id; wave w: rows +16w..+16w+15.
// acc = Ahi*Bhi + Alo*Bhi + Ahi*Blo (fp32 accum; lo*lo dropped, ~2^-18 rel).

template <int K, int F>
__device__ inline void gemm_mfma_dev(const float* __restrict__ X,
    const ushort_t* __restrict__ Bhi, const ushort_t* __restrict__ Blo,
    const float* __restrict__ dinv, ushort_t* __restrict__ T, int n, int bid) {
  constexpr int NT = F / 16;   // n-tiles
  constexpr int KS = K / 32;   // k-steps
  int wave = threadIdx.x >> 6;
  int lane = threadIdx.x & 63;
  int q = lane >> 4;
  int m = lane & 15;
  int arow = bid * 64 + wave * 16 + m;
  bool valid = arow < n;
  const float* xrow = X + (size_t)arow * K;

  f32x4 acc[NT];
#pragma unroll
  for (int t = 0; t < NT; ++t) acc[t] = (f32x4){0.f, 0.f, 0.f, 0.f};

  for (int s = 0; s < KS; ++s) {
    float av[8];
    if (valid) {
      float4 u0 = *(const float4*)(xrow + s * 32 + q * 8);
      float4 u1 = *(const float4*)(xrow + s * 32 + q * 8 + 4);
      av[0] = u0.x; av[1] = u0.y; av[2] = u0.z; av[3] = u0.w;
      av[4] = u1.x; av[5] = u1.y; av[6] = u1.z; av[7] = u1.w;
    } else {
#pragma unroll
      for (int j = 0; j < 8; ++j) av[j] = 0.f;
    }
    bf16x8 ahi, alo;
#pragma unroll
    for (int j = 0; j < 8; ++j) {
      ushort_t h = f2bf(av[j]);
      ahi[j] = (short)h;
      alo[j] = (short)f2bf(av[j] - bf2f(h));
    }
#pragma unroll
    for (int t = 0; t < NT; ++t) {
      size_t boff = (((size_t)t * KS + s) * 64 + (size_t)lane) * 8;
      bf16x8 bh = *(const bf16x8*)(Bhi + boff);
      bf16x8 bl = *(const bf16x8*)(Blo + boff);
      acc[t] = __builtin_amdgcn_mfma_f32_16x16x32_bf16(ahi, bh, acc[t], 0, 0, 0);
      acc[t] = __builtin_amdgcn_mfma_f32_16x16x32_bf16(alo, bh, acc[t], 0, 0, 0);
      acc[t] = __builtin_amdgcn_mfma_f32_16x16x32_bf16(ahi, bl, acc[t], 0, 0, 0);
    }
  }

  int orow_base = bid * 64 + wave * 16 + q * 4;
#pragma unroll
  for (int r = 0; r < 4; ++r) {
    int orow = orow_base + r;
    if (orow >= n) continue;
    float sc = dinv[orow];
    ushort_t* trow = T + (size_t)orow * F + m;
#pragma unroll
    for (int t = 0; t < NT; ++t) trow[t * 16] = f2bf(sc * acc[t][r]);
  }
}

template <int K, int F>
__global__ __launch_bounds__(256) void gemm_mfma_kernel(const float* __restrict__ X,
    const ushort_t* __restrict__ Bhi, const ushort_t* __restrict__ Blo,
    const float* __restrict__ dinv, ushort_t* __restrict__ T, int n) {
  gemm_mfma_dev<K, F>(X, Bhi, Blo, dinv, T, n, blockIdx.x);
}

// ---------- fused B: [gemm1 | fill] ----------

__global__ __launch_bounds__(256) void fusedB_kernel(
    const float* __restrict__ X, const ushort_t* __restrict__ Bhi,
    const ushort_t* __restrict__ Blo, const float* __restrict__ dinv,
    ushort_t* __restrict__ T, int n, int gblocks,
    const int* __restrict__ src, const int* __restrict__ dst,
    const int* __restrict__ slot, const int4* __restrict__ sub,
    int* __restrict__ col, int e) {
  if ((int)blockIdx.x < gblocks) {
    gemm_mfma_dev<DIN, HID>(X, Bhi, Blo, dinv, T, n, blockIdx.x);
  } else {
    int i = ((int)blockIdx.x - gblocks) * 256 + threadIdx.x;
    if (i >= e) return;
    int d = dst[i];
    int k = i & 3;
    int4 sb = sub[d];
    int base = (k == 0) ? sb.x : (k == 1) ? sb.y : (k == 2) ? sb.z : sb.w;
    col[base + slot[i]] = src[i];
  }
}

// ---------- CSR SpMM: out[d] = dinv[d]*(t'[d] + sum_c t'[c]) + b, opt ReLU ----------
// t' rows bf16, pre-scaled by dinv[row]. TWO destination nodes per wave (MLP).

template <int F, bool RELU>
__global__ __launch_bounds__(256) void spmm_kernel(const ushort_t* __restrict__ t,
    const int* __restrict__ row_start, const int* __restrict__ deg,
    const int* __restrict__ col, const float* __restrict__ dinv,
    const float* __restrict__ bias, float* __restrict__ out, int n) {
  int gw = (int)((blockIdx.x * 256u + threadIdx.x) >> 6);
  int lane = threadIdx.x & 63;
  int n0 = gw * 2;
  int n1 = n0 + 1;
  if (n0 >= n) return;
  bool h1 = (n1 < n);
  int rs0 = row_start[n0], e0 = deg[n0] - 1;
  int rs1 = h1 ? row_start[n1] : 0, e1 = h1 ? (deg[n1] - 1) : 0;
  float di0 = dinv[n0];
  float di1 = h1 ? dinv[n1] : 0.f;

  if constexpr (F == 128) {
    uint_t s0 = ((const uint_t*)(t + (size_t)n0 * F))[lane];
    float ax0 = bf2f((ushort_t)(s0 & 0xFFFF)), ay0 = bf2f((ushort_t)(s0 >> 16));
    float ax1 = 0.f, ay1 = 0.f;
    if (h1) {
      uint_t s1 = ((const uint_t*)(t + (size_t)n1 * F))[lane];
      ax1 = bf2f((ushort_t)(s1 & 0xFFFF)); ay1 = bf2f((ushort_t)(s1 >> 16));
    }
    int p0 = rs0, q0 = rs0 + e0;
    int p1 = rs1, q1 = rs1 + e1;
    while (p0 + 4 <= q0 && p1 + 4 <= q1) {
      int c[8];
      uint_t v[8];
#pragma unroll
      for (int j = 0; j < 4; ++j) { c[j] = col[p0 + j]; c[4 + j] = col[p1 + j]; }
#pragma unroll
      for (int j = 0; j < 8; ++j) v[j] = ((const uint_t*)(t + (size_t)c[j] * F))[lane];
#pragma unroll
      for (int j = 0; j < 4; ++j) {
        ax0 += bf2f((ushort_t)(v[j] & 0xFFFF));
        ay0 += bf2f((ushort_t)(v[j] >> 16));
        ax1 += bf2f((ushort_t)(v[4 + j] & 0xFFFF));
        ay1 += bf2f((ushort_t)(v[4 + j] >> 16));
      }
      p0 += 4; p1 += 4;
    }
    for (; p0 + 4 <= q0; p0 += 4) {
      int c[4]; uint_t v[4];
#pragma unroll
      for (int j = 0; j < 4; ++j) c[j] = col[p0 + j];
#pragma unroll
      for (int j = 0; j < 4; ++j) v[j] = ((const uint_t*)(t + (size_t)c[j] * F))[lane];
#pragma unroll
      for (int j = 0; j < 4; ++j) {
        ax0 += bf2f((ushort_t)(v[j] & 0xFFFF)); ay0 += bf2f((ushort_t)(v[j] >> 16));
      }
    }
    for (; p0 < q0; ++p0) {
      uint_t v = ((const uint_t*)(t + (size_t)col[p0] * F))[lane];
      ax0 += bf2f((ushort_t)(v & 0xFFFF)); ay0 += bf2f((ushort_t)(v >> 16));
    }
    for (; p1 + 4 <= q1; p1 += 4) {
      int c[4]; uint_t v[4];
#pragma unroll
      for (int j = 0; j < 4; ++j) c[j] = col[p1 + j];
#pragma unroll
      for (int j = 0; j < 4; ++j) v[j] = ((const uint_t*)(t + (size_t)c[j] * F))[lane];
#pragma unroll
      for (int j = 0; j < 4; ++j) {
        ax1 += bf2f((ushort_t)(v[j] & 0xFFFF)); ay1 += bf2f((ushort_t)(v[j] >> 16));
      }
    }
    for (; p1 < q1; ++p1) {
      uint_t v = ((const uint_t*)(t + (size_t)col[p1] * F))[lane];
      ax1 += bf2f((ushort_t)(v & 0xFFFF)); ay1 += bf2f((ushort_t)(v >> 16));
    }
    float bx = bias[2 * lane], by = bias[2 * lane + 1];
    ax0 = fmaf(di0, ax0, bx); ay0 = fmaf(di0, ay0, by);
    if constexpr (RELU) { ax0 = fmaxf(ax0, 0.f); ay0 = fmaxf(ay0, 0.f); }
    float2 o0; o0.x = ax0; o0.y = ay0;
    ((float2*)(out + (size_t)n0 * F))[lane] = o0;
    if (h1) {
      ax1 = fmaf(di1, ax1, bx); ay1 = fmaf(di1, ay1, by);
      if constexpr (RELU) { ax1 = fmaxf(ax1, 0.f); ay1 = fmaxf(ay1, 0.f); }
      float2 o1; o1.x = ax1; o1.y = ay1;
      ((float2*)(out + (size_t)n1 * F))[lane] = o1;
    }
  } else {  // F == 64: one bf16 per lane
    float a0 = bf2f(t[(size_t)n0 * F + lane]);
    float a1 = h1 ? bf2f(t[(size_t)n1 * F + lane]) : 0.f;
    int p0 = rs0, q0 = rs0 + e0;
    int p1 = rs1, q1 = rs1 + e1;
    while (p0 + 4 <= q0 && p1 + 4 <= q1) {
      int c[8];
      ushort_t v[8];
#pragma unroll
      for (int j = 0; j < 4; ++j) { c[j] = col[p0 + j]; c[4 + j] = col[p1 + j]; }
#pragma unroll
      for (int j = 0; j < 8; ++j) v[j] = t[(size_t)c[j] * F + lane];
#pragma unroll
      for (int j = 0; j < 4; ++j) { a0 += bf2f(v[j]); a1 += bf2f(v[4 + j]); }
      p0 += 4; p1 += 4;
    }
    for (; p0 + 4 <= q0; p0 += 4) {
      int c[4]; ushort_t v[4];
#pragma unroll
      for (int j = 0; j < 4; ++j) c[j] = col[p0 + j];
#pragma unroll
      for (int j = 0; j < 4; ++j) v[j] = t[(size_t)c[j] * F + lane];
#pragma unroll
      for (int j = 0; j < 4; ++j) a0 += bf2f(v[j]);
    }
    for (; p0 < q0; ++p0) a0 += bf2f(t[(size_t)col[p0] * F + lane]);
    for (; p1 + 4 <= q1; p1 += 4) {
      int c[4]; ushort_t v[4];
#pragma unroll
      for (int j = 0; j < 4; ++j) c[j] = col[p1 + j];
#pragma unroll
      for (int j = 0; j < 4; ++j) v[j] = t[(size_t)c[j] * F + lane];
#pragma unroll
      for (int j = 0; j < 4; ++j) a1 += bf2f(v[j]);
    }
    for (; p1 < q1; ++p1) a1 += bf2f(t[(size_t)col[p1] * F + lane]);
    float b = bias[lane];
    a0 = fmaf(di0, a0, b);
    if constexpr (RELU) a0 = fmaxf(a0, 0.f);
    out[(size_t)n0 * F + lane] = a0;
    if (h1) {
      a1 = fmaf(di1, a1, b);
      if constexpr (RELU) a1 = fmaxf(a1, 0.f);
      out[(size_t)n1 * F + lane] = a1;
    }
  }
}

// ---------- launch ----------

extern "C" void kernel_launch(void* const* d_in, const int* in_sizes, int n_in,
                              void* d_out, int out_size, void* d_ws, size_t ws_size,
                              hipStream_t stream) {
  const float* x  = (const float*)d_in[0];
  const float* W1 = (const float*)d_in[1];
  const float* b1 = (const float*)d_in[2];
  const float* W2 = (const float*)d_in[3];
  const float* b2 = (const float*)d_in[4];
  const float* W3 = (const float*)d_in[5];
  const float* b3 = (const float*)d_in[6];
  const int* ei   = (const int*)d_in[7];  // harness delivers integers as int32

  int n = in_sizes[0] / DIN;
  int e = in_sizes[7] / 2;
  const int* src = ei;
  const int* dst = ei + e;

  char* ws = (char*)d_ws;
  size_t off = 0;
  auto alloc = [&](size_t bytes) -> void* {
    off = (off + 255) & ~(size_t)255;
    void* p = ws + off;
    off += bytes;
    return p;
  };
  int nscan = (n + 1023) / 1024;
  int*      c0        = (int*)alloc((size_t)n * 4);
  int*      c1        = (int*)alloc((size_t)n * 4);
  int*      c2        = (int*)alloc((size_t)n * 4);
  int*      c3        = (int*)alloc((size_t)n * 4);
  int*      deg       = (int*)alloc((size_t)n * 4);
  float*    dinv      = (float*)alloc((size_t)n * 4);
  int*      row_start = (int*)alloc((size_t)n * 4);
  int4*     sub       = (int4*)alloc((size_t)n * 16);
  int*      blocksum  = (int*)alloc((size_t)nscan * 4);
  int*      slot      = (int*)alloc((size_t)e * 4);
  int*      col       = (int*)alloc((size_t)e * 4);
  ushort_t* T         = (ushort_t*)alloc((size_t)n * HID * 2);  // bf16 GEMM out
  float*    Hf        = (float*)alloc((size_t)n * HID * 4);     // fp32 SpMM out
  ushort_t* W1hi      = (ushort_t*)alloc((size_t)DIN * HID * 2);
  ushort_t* W1lo      = (ushort_t*)alloc((size_t)DIN * HID * 2);
  ushort_t* W2hi      = (ushort_t*)alloc((size_t)HID * HID * 2);
  ushort_t* W2lo      = (ushort_t*)alloc((size_t)HID * HID * 2);
  ushort_t* W3hi      = (ushort_t*)alloc((size_t)HID * DOUT * 2);
  ushort_t* W3lo      = (ushort_t*)alloc((size_t)HID * DOUT * 2);
  (void)ws_size;

  int nb256 = (n + 255) / 256;
  int eb256 = (e + 255) / 256;
  int gemm_blocks = (n + 63) / 64;
  int nwaves = (n + 1) / 2;                 // 2 nodes per wave
  int spmm_blocks = (nwaves + 3) / 4;       // 4 waves per block
  constexpr int WPREP_TOTAL = DIN * HID + HID * HID + HID * DOUT;  // 57344
  int wblocks = (WPREP_TOTAL + 255) / 256;  // 224

  init_deg_kernel<<<nb256, 256, 0, stream>>>(c0, c1, c2, c3, n);
  fusedA_kernel<<<wblocks + eb256, 256, 0, stream>>>(
      W1, W1hi, W1lo, W2, W2hi, W2lo, W3, W3hi, W3lo,
      dst, c0, c1, c2, c3, slot, e, wblocks);
  scanA_kernel<<<nscan, 256, 0, stream>>>(c0, c1, c2, c3, blocksum, n);
  scanB_kernel<<<1, 64, 0, stream>>>(blocksum, nscan);
  scanC_kernel<<<nscan, 256, 0, stream>>>(c0, c1, c2, c3, blocksum, row_start, deg, dinv, sub, n);
  fusedB_kernel<<<gemm_blocks + eb256, 256, 0, stream>>>(
      x, W1hi, W1lo, dinv, T, n, gemm_blocks,
      src, dst, slot, sub, col, e);

  spmm_kernel<HID, true><<<spmm_blocks, 256, 0, stream>>>(T, row_start, deg, col, dinv, b1, Hf, n);
  gemm_mfma_kernel<HID, HID><<<gemm_blocks, 256, 0, stream>>>(Hf, W2hi, W2lo, dinv, T, n);
  spmm_kernel<HID, true><<<spmm_blocks, 256, 0, stream>>>(T, row_start, deg, col, dinv, b2, Hf, n);
  gemm_mfma_kernel<HID, DOUT><<<gemm_blocks, 256, 0, stream>>>(Hf, W3hi, W3lo, dinv, T, n);
  spmm_kernel<DOUT, false><<<spmm_blocks, 256, 0, stream>>>(T, row_start, deg, col, dinv, b3, (float*)d_out, n);
}

// Round 10
// 404.591 us; speedup vs baseline: 2.0362x; 1.0198x over previous
//
#include <hip/hip_runtime.h>

// GCN 3-layer: N=50000, E=1.6M, D_IN=256, H=128, D_OUT=64, fp32 in/out.
// CSR build: 4-way split-atomic degree pass (atomic return = slot), parallel
// scan with int4 sub-base table, atomic-free scatter fill.
// Per layer: split-bf16 MFMA GEMM -> CSR-SpMM over bf16 rows.
// Round 10: overlap gemm1 (MFMA-bound) with deg_slot (atomic-latency-bound) —
// gemm1 writes UNSCALED T (no dinv dep); dinv applied by scaleT fused w/ fill.

constexpr int DIN = 256;
constexpr int HID = 128;
constexpr int DOUT = 64;

typedef unsigned short ushort_t;
typedef unsigned int uint_t;
typedef __attribute__((ext_vector_type(8))) short bf16x8;
typedef __attribute__((ext_vector_type(4))) float f32x4;

__device__ inline ushort_t f2bf(float f) {
  uint_t u = __float_as_uint(f);
  u += 0x7FFF + ((u >> 16) & 1);  // RNE
  return (ushort_t)(u >> 16);
}
__device__ inline float bf2f(ushort_t b) {
  return __uint_as_float(((uint_t)b) << 16);
}

// ---------- weight prep (device fn): W[K][F] fp32 -> fragment bf16 hi/lo ----------
// Layout: Bp[t = n/16][s = k/32][lane = (k/8 % 4)*16 + n%16][j = k%8]

__device__ inline void wprep_one(const float* __restrict__ W, ushort_t* __restrict__ Bhi,
                                 ushort_t* __restrict__ Blo, int K, int F, int i) {
  int k = i / F, nn = i % F;
  int t = nn >> 4, s = k >> 5, q = (k >> 3) & 3, j = k & 7;
  int lane = q * 16 + (nn & 15);
  int KS = K >> 5;
  size_t idx = (((size_t)t * KS + s) * 64 + (size_t)lane) * 8 + j;
  float w = W[i];
  ushort_t h = f2bf(w);
  float r = w - bf2f(h);
  Bhi[idx] = h;
  Blo[idx] = f2bf(r);
}

// ---------- init counters + wprep x3 (independent) ----------

__global__ __launch_bounds__(256) void initprep_kernel(
    int* __restrict__ c0, int* __restrict__ c1, int* __restrict__ c2,
    int* __restrict__ c3, int n, int iblocks,
    const float* __restrict__ W1, ushort_t* __restrict__ W1hi, ushort_t* __restrict__ W1lo,
    const float* __restrict__ W2, ushort_t* __restrict__ W2hi, ushort_t* __restrict__ W2lo,
    const float* __restrict__ W3, ushort_t* __restrict__ W3hi, ushort_t* __restrict__ W3lo) {
  if ((int)blockIdx.x < iblocks) {
    int i = blockIdx.x * 256 + threadIdx.x;
    if (i < n) { c0[i] = 1; c1[i] = 0; c2[i] = 0; c3[i] = 0; }  // self-loop in c0
  } else {
    int idx = ((int)blockIdx.x - iblocks) * 256 + threadIdx.x;
    constexpr int S1 = DIN * HID;        // 32768
    constexpr int S2 = S1 + HID * HID;   // 49152
    constexpr int S3 = S2 + HID * DOUT;  // 57344
    if (idx < S1) wprep_one(W1, W1hi, W1lo, DIN, HID, idx);
    else if (idx < S2) wprep_one(W2, W2hi, W2lo, HID, HID, idx - S1);
    else if (idx < S3) wprep_one(W3, W3hi, W3lo, HID, DOUT, idx - S2);
  }
}

// ---------- split-bf16 MFMA GEMM (device fn) ----------
// 256 threads = 4 waves; 64 rows per block-id; wave w: rows +16w..+16w+15.
// acc = Ahi*Bhi + Alo*Bhi + Ahi*Blo (fp32 accum; lo*lo dropped, ~2^-18 rel).

template <int K, int F, bool SCALE>
__device__ inline void gemm_mfma_dev(const float* __restrict__ X,
    const ushort_t* __restrict__ Bhi, const ushort_t* __restrict__ Blo,
    const float* __restrict__ dinv, ushort_t* __restrict__ T, int n, int bid) {
  constexpr int NT = F / 16;   // n-tiles
  constexpr int KS = K / 32;   // k-steps
  int wave = threadIdx.x >> 6;
  int lane = threadIdx.x & 63;
  int q = lane >> 4;
  int m = lane & 15;
  int arow = bid * 64 + wave * 16 + m;
  bool valid = arow < n;
  const float* xrow = X + (size_t)arow * K;

  f32x4 acc[NT];
#pragma unroll
  for (int t = 0; t < NT; ++t) acc[t] = (f32x4){0.f, 0.f, 0.f, 0.f};

  for (int s = 0; s < KS; ++s) {
    float av[8];
    if (valid) {
      float4 u0 = *(const float4*)(xrow + s * 32 + q * 8);
      float4 u1 = *(const float4*)(xrow + s * 32 + q * 8 + 4);
      av[0] = u0.x; av[1] = u0.y; av[2] = u0.z; av[3] = u0.w;
      av[4] = u1.x; av[5] = u1.y; av[6] = u1.z; av[7] = u1.w;
    } else {
#pragma unroll
      for (int j = 0; j < 8; ++j) av[j] = 0.f;
    }
    bf16x8 ahi, alo;
#pragma unroll
    for (int j = 0; j < 8; ++j) {
      ushort_t h = f2bf(av[j]);
      ahi[j] = (short)h;
      alo[j] = (short)f2bf(av[j] - bf2f(h));
    }
#pragma unroll
    for (int t = 0; t < NT; ++t) {
      size_t boff = (((size_t)t * KS + s) * 64 + (size_t)lane) * 8;
      bf16x8 bh = *(const bf16x8*)(Bhi + boff);
      bf16x8 bl = *(const bf16x8*)(Blo + boff);
      acc[t] = __builtin_amdgcn_mfma_f32_16x16x32_bf16(ahi, bh, acc[t], 0, 0, 0);
      acc[t] = __builtin_amdgcn_mfma_f32_16x16x32_bf16(alo, bh, acc[t], 0, 0, 0);
      acc[t] = __builtin_amdgcn_mfma_f32_16x16x32_bf16(ahi, bl, acc[t], 0, 0, 0);
    }
  }

  int orow_base = bid * 64 + wave * 16 + q * 4;
#pragma unroll
  for (int r = 0; r < 4; ++r) {
    int orow = orow_base + r;
    if (orow >= n) continue;
    float sc = SCALE ? dinv[orow] : 1.0f;
    ushort_t* trow = T + (size_t)orow * F + m;
#pragma unroll
    for (int t = 0; t < NT; ++t) trow[t * 16] = f2bf(sc * acc[t][r]);
  }
}

template <int K, int F>
__global__ __launch_bounds__(256) void gemm_mfma_kernel(const float* __restrict__ X,
    const ushort_t* __restrict__ Bhi, const ushort_t* __restrict__ Blo,
    const float* __restrict__ dinv, ushort_t* __restrict__ T, int n) {
  gemm_mfma_dev<K, F, true>(X, Bhi, Blo, dinv, T, n, blockIdx.x);
}

// ---------- fused A: [gemm1 unscaled | deg_slot] ----------
// gemm1 waves use MFMA/VALU; deg_slot waves idle on atomics -> complementary.

__global__ __launch_bounds__(256) void fusedA_kernel(
    const float* __restrict__ X, const ushort_t* __restrict__ Bhi,
    const ushort_t* __restrict__ Blo, ushort_t* __restrict__ T, int n, int gblocks,
    const int* __restrict__ dst, int* __restrict__ c0, int* __restrict__ c1,
    int* __restrict__ c2, int* __restrict__ c3, int* __restrict__ slot, int e) {
  if ((int)blockIdx.x < gblocks) {
    gemm_mfma_dev<DIN, HID, false>(X, Bhi, Blo, nullptr, T, n, blockIdx.x);
  } else {
    int i = ((int)blockIdx.x - gblocks) * 256 + threadIdx.x;
    if (i >= e) return;
    int d = dst[i];
    int k = i & 3;
    int s;
    if      (k == 0) s = atomicAdd(&c0[d], 1);  // >= 1
    else if (k == 1) s = atomicAdd(&c1[d], 1);  // >= 0
    else if (k == 2) s = atomicAdd(&c2[d], 1);
    else             s = atomicAdd(&c3[d], 1);
    slot[i] = s;
  }
}

// ---------- 3-phase exclusive scan of (deg-1), 1024 elems / block ----------

__global__ __launch_bounds__(256) void scanA_kernel(const int* __restrict__ c0,
    const int* __restrict__ c1, const int* __restrict__ c2, const int* __restrict__ c3,
    int* __restrict__ blocksum, int n) {
  __shared__ int sums[256];
  int t = threadIdx.x;
  int base = blockIdx.x * 1024 + t * 4;
  int local = 0;
#pragma unroll
  for (int k = 0; k < 4; ++k) {
    int i = base + k;
    if (i < n) local += c0[i] + c1[i] + c2[i] + c3[i] - 1;
  }
  sums[t] = local;
  __syncthreads();
  for (int off = 128; off > 0; off >>= 1) {
    if (t < off) sums[t] += sums[t + off];
    __syncthreads();
  }
  if (t == 0) blocksum[blockIdx.x] = sums[0];
}

__global__ __launch_bounds__(64) void scanB_kernel(int* __restrict__ blocksum, int nb) {
  int lane = threadIdx.x;
  int carry = 0;
  for (int base = 0; base < nb; base += 64) {
    int i = base + lane;
    int orig = (i < nb) ? blocksum[i] : 0;
    int v = orig;
#pragma unroll
    for (int off = 1; off < 64; off <<= 1) {
      int u = __shfl_up(v, off, 64);
      if (lane >= off) v += u;
    }
    int total = __shfl(v, 63, 64);
    if (i < nb) blocksum[i] = carry + v - orig;  // exclusive
    carry += total;
  }
}

__global__ __launch_bounds__(256) void scanC_kernel(const int* __restrict__ c0,
    const int* __restrict__ c1, const int* __restrict__ c2, const int* __restrict__ c3,
    const int* __restrict__ blocksum, int* __restrict__ row_start, int* __restrict__ deg,
    float* __restrict__ dinv, int4* __restrict__ sub, int n) {
  __shared__ int sums[256];
  int t = threadIdx.x;
  int base = blockIdx.x * 1024 + t * 4;
  int d[4], k0[4], k1[4], k2[4];
  int local = 0;
#pragma unroll
  for (int k = 0; k < 4; ++k) {
    int i = base + k;
    if (i < n) {
      k0[k] = c0[i]; k1[k] = c1[i]; k2[k] = c2[i];
      d[k] = k0[k] + k1[k] + k2[k] + c3[i];
      local += d[k] - 1;
    } else { d[k] = 1; k0[k] = 1; k1[k] = 0; k2[k] = 0; }
  }
  sums[t] = local;
  __syncthreads();
  for (int off = 1; off < 256; off <<= 1) {
    int v = (t >= off) ? sums[t - off] : 0;
    __syncthreads();
    sums[t] += v;
    __syncthreads();
  }
  int run = blocksum[blockIdx.x] + sums[t] - local;  // exclusive offset
#pragma unroll
  for (int k = 0; k < 4; ++k) {
    int i = base + k;
    if (i < n) {
      row_start[i] = run;
      deg[i] = d[k];
      dinv[i] = rsqrtf((float)d[k]);
      int4 sb;
      sb.x = run - 1;                  // class 0: slot >= 1 -> pos = run-1+slot
      sb.y = run + (k0[k] - 1);        // class 1: slot >= 0
      sb.z = sb.y + k1[k];             // class 2
      sb.w = sb.z + k2[k];             // class 3
      sub[i] = sb;
      run += d[k] - 1;
    }
  }
}

// ---------- fused B: [fill | scaleT] ----------
// fill: atomic-free scatter. scaleT: T[row] *= dinv[row] in place (bf16).

__global__ __launch_bounds__(256) void fusedB_kernel(
    const int* __restrict__ src, const int* __restrict__ dst,
    const int* __restrict__ slot, const int4* __restrict__ sub,
    int* __restrict__ col, int e, int fblocks,
    ushort_t* __restrict__ T, const float* __restrict__ dinv, int n) {
  if ((int)blockIdx.x < fblocks) {
    int i = blockIdx.x * 256 + threadIdx.x;
    if (i >= e) return;
    int d = dst[i];
    int k = i & 3;
    int4 sb = sub[d];
    int base = (k == 0) ? sb.x : (k == 1) ? sb.y : (k == 2) ? sb.z : sb.w;
    col[base + slot[i]] = src[i];
  } else {
    int idx = ((int)blockIdx.x - fblocks) * 256 + threadIdx.x;  // 8 bf16 each
    int total = n * (HID / 8);
    if (idx >= total) return;
    int row = idx >> 4;  // 16 chunks of 8 per row (HID=128)
    float sc = dinv[row];
    uint4* p = (uint4*)T + idx;
    uint4 v = *p;
    uint_t w[4] = {v.x, v.y, v.z, v.w};
#pragma unroll
    for (int j = 0; j < 4; ++j) {
      float lo = sc * bf2f((ushort_t)(w[j] & 0xFFFF));
      float hi = sc * bf2f((ushort_t)(w[j] >> 16));
      w[j] = (uint_t)f2bf(lo) | ((uint_t)f2bf(hi) << 16);
    }
    v.x = w[0]; v.y = w[1]; v.z = w[2]; v.w = w[3];
    *p = v;
  }
}

// ---------- CSR SpMM: out[d] = dinv[d]*(t'[d] + sum_c t'[c]) + b, opt ReLU ----------
// t' rows bf16, pre-scaled by dinv[row]. TWO destination nodes per wave (MLP).

template <int F, bool RELU>
__global__ __launch_bounds__(256) void spmm_kernel(const ushort_t* __restrict__ t,
    const int* __restrict__ row_start, const int* __restrict__ deg,
    const int* __restrict__ col, const float* __restrict__ dinv,
    const float* __restrict__ bias, float* __restrict__ out, int n) {
  int gw = (int)((blockIdx.x * 256u + threadIdx.x) >> 6);
  int lane = threadIdx.x & 63;
  int n0 = gw * 2;
  int n1 = n0 + 1;
  if (n0 >= n) return;
  bool h1 = (n1 < n);
  int rs0 = row_start[n0], e0 = deg[n0] - 1;
  int rs1 = h1 ? row_start[n1] : 0, e1 = h1 ? (deg[n1] - 1) : 0;
  float di0 = dinv[n0];
  float di1 = h1 ? dinv[n1] : 0.f;

  if constexpr (F == 128) {
    uint_t s0 = ((const uint_t*)(t + (size_t)n0 * F))[lane];
    float ax0 = bf2f((ushort_t)(s0 & 0xFFFF)), ay0 = bf2f((ushort_t)(s0 >> 16));
    float ax1 = 0.f, ay1 = 0.f;
    if (h1) {
      uint_t s1 = ((const uint_t*)(t + (size_t)n1 * F))[lane];
      ax1 = bf2f((ushort_t)(s1 & 0xFFFF)); ay1 = bf2f((ushort_t)(s1 >> 16));
    }
    int p0 = rs0, q0 = rs0 + e0;
    int p1 = rs1, q1 = rs1 + e1;
    while (p0 + 4 <= q0 && p1 + 4 <= q1) {
      int c[8];
      uint_t v[8];
#pragma unroll
      for (int j = 0; j < 4; ++j) { c[j] = col[p0 + j]; c[4 + j] = col[p1 + j]; }
#pragma unroll
      for (int j = 0; j < 8; ++j) v[j] = ((const uint_t*)(t + (size_t)c[j] * F))[lane];
#pragma unroll
      for (int j = 0; j < 4; ++j) {
        ax0 += bf2f((ushort_t)(v[j] & 0xFFFF));
        ay0 += bf2f((ushort_t)(v[j] >> 16));
        ax1 += bf2f((ushort_t)(v[4 + j] & 0xFFFF));
        ay1 += bf2f((ushort_t)(v[4 + j] >> 16));
      }
      p0 += 4; p1 += 4;
    }
    for (; p0 + 4 <= q0; p0 += 4) {
      int c[4]; uint_t v[4];
#pragma unroll
      for (int j = 0; j < 4; ++j) c[j] = col[p0 + j];
#pragma unroll
      for (int j = 0; j < 4; ++j) v[j] = ((const uint_t*)(t + (size_t)c[j] * F))[lane];
#pragma unroll
      for (int j = 0; j < 4; ++j) {
        ax0 += bf2f((ushort_t)(v[j] & 0xFFFF)); ay0 += bf2f((ushort_t)(v[j] >> 16));
      }
    }
    for (; p0 < q0; ++p0) {
      uint_t v = ((const uint_t*)(t + (size_t)col[p0] * F))[lane];
      ax0 += bf2f((ushort_t)(v & 0xFFFF)); ay0 += bf2f((ushort_t)(v >> 16));
    }
    for (; p1 + 4 <= q1; p1 += 4) {
      int c[4]; uint_t v[4];
#pragma unroll
      for (int j = 0; j < 4; ++j) c[j] = col[p1 + j];
#pragma unroll
      for (int j = 0; j < 4; ++j) v[j] = ((const uint_t*)(t + (size_t)c[j] * F))[lane];
#pragma unroll
      for (int j = 0; j < 4; ++j) {
        ax1 += bf2f((ushort_t)(v[j] & 0xFFFF)); ay1 += bf2f((ushort_t)(v[j] >> 16));
      }
    }
    for (; p1 < q1; ++p1) {
      uint_t v = ((const uint_t*)(t + (size_t)col[p1] * F))[lane];
      ax1 += bf2f((ushort_t)(v & 0xFFFF)); ay1 += bf2f((ushort_t)(v >> 16));
    }
    float bx = bias[2 * lane], by = bias[2 * lane + 1];
    ax0 = fmaf(di0, ax0, bx); ay0 = fmaf(di0, ay0, by);
    if constexpr (RELU) { ax0 = fmaxf(ax0, 0.f); ay0 = fmaxf(ay0, 0.f); }
    float2 o0; o0.x = ax0; o0.y = ay0;
    ((float2*)(out + (size_t)n0 * F))[lane] = o0;
    if (h1) {
      ax1 = fmaf(di1, ax1, bx); ay1 = fmaf(di1, ay1, by);
      if constexpr (RELU) { ax1 = fmaxf(ax1, 0.f); ay1 = fmaxf(ay1, 0.f); }
      float2 o1; o1.x = ax1; o1.y = ay1;
      ((float2*)(out + (size_t)n1 * F))[lane] = o1;
    }
  } else {  // F == 64: one bf16 per lane
    float a0 = bf2f(t[(size_t)n0 * F + lane]);
    float a1 = h1 ? bf2f(t[(size_t)n1 * F + lane]) : 0.f;
    int p0 = rs0, q0 = rs0 + e0;
    int p1 = rs1, q1 = rs1 + e1;
    while (p0 + 4 <= q0 && p1 + 4 <= q1) {
      int c[8];
      ushort_t v[8];
#pragma unroll
      for (int j = 0; j < 4; ++j) { c[j] = col[p0 + j]; c[4 + j] = col[p1 + j]; }
#pragma unroll
      for (int j = 0; j < 8; ++j) v[j] = t[(size_t)c[j] * F + lane];
#pragma unroll
      for (int j = 0; j < 4; ++j) { a0 += bf2f(v[j]); a1 += bf2f(v[4 + j]); }
      p0 += 4; p1 += 4;
    }
    for (; p0 + 4 <= q0; p0 += 4) {
      int c[4]; ushort_t v[4];
#pragma unroll
      for (int j = 0; j < 4; ++j) c[j] = col[p0 + j];
#pragma unroll
      for (int j = 0; j < 4; ++j) v[j] = t[(size_t)c[j] * F + lane];
#pragma unroll
      for (int j = 0; j < 4; ++j) a0 += bf2f(v[j]);
    }
    for (; p0 < q0; ++p0) a0 += bf2f(t[(size_t)col[p0] * F + lane]);
    for (; p1 + 4 <= q1; p1 += 4) {
      int c[4]; ushort_t v[4];
#pragma unroll
      for (int j = 0; j < 4; ++j) c[j] = col[p1 + j];
#pragma unroll
      for (int j = 0; j < 4; ++j) v[j] = t[(size_t)c[j] * F + lane];
#pragma unroll
      for (int j = 0; j < 4; ++j) a1 += bf2f(v[j]);
    }
    for (; p1 < q1; ++p1) a1 += bf2f(t[(size_t)col[p1] * F + lane]);
    float b = bias[lane];
    a0 = fmaf(di0, a0, b);
    if constexpr (RELU) a0 = fmaxf(a0, 0.f);
    out[(size_t)n0 * F + lane] = a0;
    if (h1) {
      a1 = fmaf(di1, a1, b);
      if constexpr (RELU) a1 = fmaxf(a1, 0.f);
      out[(size_t)n1 * F + lane] = a1;
    }
  }
}

// ---------- launch ----------

extern "C" void kernel_launch(void* const* d_in, const int* in_sizes, int n_in,
                              void* d_out, int out_size, void* d_ws, size_t ws_size,
                              hipStream_t stream) {
  const float* x  = (const float*)d_in[0];
  const float* W1 = (const float*)d_in[1];
  const float* b1 = (const float*)d_in[2];
  const float* W2 = (const float*)d_in[3];
  const float* b2 = (const float*)d_in[4];
  const float* W3 = (const float*)d_in[5];
  const float* b3 = (const float*)d_in[6];
  const int* ei   = (const int*)d_in[7];  // harness delivers integers as int32

  int n = in_sizes[0] / DIN;
  int e = in_sizes[7] / 2;
  const int* src = ei;
  const int* dst = ei + e;

  char* ws = (char*)d_ws;
  size_t off = 0;
  auto alloc = [&](size_t bytes) -> void* {
    off = (off + 255) & ~(size_t)255;
    void* p = ws + off;
    off += bytes;
    return p;
  };
  int nscan = (n + 1023) / 1024;
  int*      c0        = (int*)alloc((size_t)n * 4);
  int*      c1        = (int*)alloc((size_t)n * 4);
  int*      c2        = (int*)alloc((size_t)n * 4);
  int*      c3        = (int*)alloc((size_t)n * 4);
  int*      deg       = (int*)alloc((size_t)n * 4);
  float*    dinv      = (float*)alloc((size_t)n * 4);
  int*      row_start = (int*)alloc((size_t)n * 4);
  int4*     sub       = (int4*)alloc((size_t)n * 16);
  int*      blocksum  = (int*)alloc((size_t)nscan * 4);
  int*      slot      = (int*)alloc((size_t)e * 4);
  int*      col       = (int*)alloc((size_t)e * 4);
  ushort_t* T         = (ushort_t*)alloc((size_t)n * HID * 2);  // bf16 GEMM out
  float*    Hf        = (float*)alloc((size_t)n * HID * 4);     // fp32 SpMM out
  ushort_t* W1hi      = (ushort_t*)alloc((size_t)DIN * HID * 2);
  ushort_t* W1lo      = (ushort_t*)alloc((size_t)DIN * HID * 2);
  ushort_t* W2hi      = (ushort_t*)alloc((size_t)HID * HID * 2);
  ushort_t* W2lo      = (ushort_t*)alloc((size_t)HID * HID * 2);
  ushort_t* W3hi      = (ushort_t*)alloc((size_t)HID * DOUT * 2);
  ushort_t* W3lo      = (ushort_t*)alloc((size_t)HID * DOUT * 2);
  (void)ws_size;

  int nb256 = (n + 255) / 256;
  int eb256 = (e + 255) / 256;
  int gemm_blocks = (n + 63) / 64;
  int nwaves = (n + 1) / 2;                 // 2 nodes per wave
  int spmm_blocks = (nwaves + 3) / 4;       // 4 waves per block
  constexpr int WPREP_TOTAL = DIN * HID + HID * HID + HID * DOUT;  // 57344
  int wblocks = (WPREP_TOTAL + 255) / 256;  // 224
  int sblocks = (n * (HID / 8) + 255) / 256;  // scaleT blocks (8 bf16/thread)

  initprep_kernel<<<nb256 + wblocks, 256, 0, stream>>>(
      c0, c1, c2, c3, n, nb256,
      W1, W1hi, W1lo, W2, W2hi, W2lo, W3, W3hi, W3lo);
  fusedA_kernel<<<gemm_blocks + eb256, 256, 0, stream>>>(
      x, W1hi, W1lo, T, n, gemm_blocks,
      dst, c0, c1, c2, c3, slot, e);
  scanA_kernel<<<nscan, 256, 0, stream>>>(c0, c1, c2, c3, blocksum, n);
  scanB_kernel<<<1, 64, 0, stream>>>(blocksum, nscan);
  scanC_kernel<<<nscan, 256, 0, stream>>>(c0, c1, c2, c3, blocksum, row_start, deg, dinv, sub, n);
  fusedB_kernel<<<eb256 + sblocks, 256, 0, stream>>>(
      src, dst, slot, sub, col, e, eb256, T, dinv, n);

  spmm_kernel<HID, true><<<spmm_blocks, 256, 0, stream>>>(T, row_start, deg, col, dinv, b1, Hf, n);
  gemm_mfma_kernel<HID, HID><<<gemm_blocks, 256, 0, stream>>>(Hf, W2hi, W2lo, dinv, T, n);
  spmm_kernel<HID, true><<<spmm_blocks, 256, 0, stream>>>(T, row_start, deg, col, dinv, b2, Hf, n);
  gemm_mfma_kernel<HID, DOUT><<<gemm_blocks, 256, 0, stream>>>(Hf, W3hi, W3lo, dinv, T, n);
  spmm_kernel<DOUT, false><<<spmm_blocks, 256, 0, stream>>>(T, row_start, deg, col, dinv, b3, (float*)d_out, n);
}